// Round 9
// baseline (247.430 us; speedup 1.0000x reference)
//
#include <hip/hip_runtime.h>
#include <hip/hip_bf16.h>

// GCN encoder: out = GCNconv2( relu(GCNconv1(x)) )
// GCNconv(h,W,b) = D^-1/2 (A+I) D^-1/2 (h W) + b
//
// R8: barrier-free MFMA GEMM. W fragments read directly from global
//   (L2/L1-resident: W1sp 128KB, W2sp 32KB shared by all blocks) -> no LDS,
//   no __syncthreads, waves pipeline independently; A reg-prefetch 1 step.
//   CSR build + bf16 gather agg unchanged from R6.

#define GCN_IN_C 256
#define GCN_HID  128
#define GCN_OUT  64

#define BKT_SHIFT 8
#define BKT_NODES 256
#define EPB 4096  // edges per block in partition kernels

typedef __bf16 bf16x8 __attribute__((ext_vector_type(8)));
typedef float f32x4 __attribute__((ext_vector_type(4)));

__global__ __launch_bounds__(256) void k_zero_i32(int* __restrict__ p, int n) {
  int i = blockIdx.x * 256 + threadIdx.x;
  if (i < n) p[i] = 0;
}

// P1a: bucket sizes
__global__ __launch_bounds__(256) void k_bucket_hist(const int* __restrict__ dst,
                                                     int* __restrict__ bcnt, int e, int nb) {
  __shared__ int h[512];
  int tid = threadIdx.x;
  h[tid] = 0; h[tid + 256] = 0;
  __syncthreads();
  int base = blockIdx.x * EPB;
#pragma unroll
  for (int j = 0; j < EPB / 256; ++j) {
    int i = base + j * 256 + tid;
    if (i < e) atomicAdd(&h[dst[i] >> BKT_SHIFT], 1);
  }
  __syncthreads();
  if (tid < nb && h[tid]) atomicAdd(&bcnt[tid], h[tid]);
  if (tid + 256 < nb && h[tid + 256]) atomicAdd(&bcnt[tid + 256], h[tid + 256]);
}

// exclusive scan of bucket sizes (nb <= 512), writes bbase and bcur
__global__ __launch_bounds__(512) void k_scan_buckets(const int* __restrict__ bcnt,
                                                      int* __restrict__ bbase,
                                                      int* __restrict__ bcur, int nb) {
  __shared__ int sh[512];
  int t = threadIdx.x;
  int v = (t < nb) ? bcnt[t] : 0;
  sh[t] = v;
  __syncthreads();
  for (int d = 1; d < 512; d <<= 1) {
    int x = (t >= d) ? sh[t - d] : 0;
    __syncthreads();
    sh[t] += x;
    __syncthreads();
  }
  if (t < nb) {
    int ex = sh[t] - v;
    bbase[t] = ex;
    bcur[t] = ex;
  }
}

// P1b: partition edges into bucket-contiguous regions (packed 4B)
__global__ __launch_bounds__(256) void k_partition(const int* __restrict__ src,
                                                   const int* __restrict__ dst,
                                                   int* __restrict__ bcur,
                                                   unsigned int* __restrict__ part,
                                                   int e, int nb) {
  __shared__ int h[512];
  __shared__ int base[512];
  int tid = threadIdx.x;
  h[tid] = 0; h[tid + 256] = 0;
  __syncthreads();
  int b0 = blockIdx.x * EPB;
  int s[EPB / 256], d[EPB / 256], rk[EPB / 256];
#pragma unroll
  for (int j = 0; j < EPB / 256; ++j) {
    int i = b0 + j * 256 + tid;
    if (i < e) {
      s[j] = src[i];
      d[j] = dst[i];
      rk[j] = atomicAdd(&h[d[j] >> BKT_SHIFT], 1);
    }
  }
  __syncthreads();
  if (tid < nb && h[tid]) base[tid] = atomicAdd(&bcur[tid], h[tid]);
  if (tid + 256 < nb && h[tid + 256]) base[tid + 256] = atomicAdd(&bcur[tid + 256], h[tid + 256]);
  __syncthreads();
#pragma unroll
  for (int j = 0; j < EPB / 256; ++j) {
    int i = b0 + j * 256 + tid;
    if (i < e) {
      int bk = d[j] >> BKT_SHIFT;
      unsigned int dl = (unsigned int)(d[j] & (BKT_NODES - 1));
      part[base[bk] + rk[j]] = (dl << 24) | (unsigned int)s[j];
    }
  }
}

// P2: per-bucket CSR finalize. One block per bucket.
__global__ __launch_bounds__(256) void k_bucket_csr(
    const unsigned int* __restrict__ part, const int* __restrict__ bbase,
    const int* __restrict__ bcnt, int* __restrict__ off, int* __restrict__ end,
    float* __restrict__ dis, int* __restrict__ csr, int n) {
  __shared__ int cnt[256];
  __shared__ int sc[256];
  __shared__ int cur[256];
  int b = blockIdx.x, tid = threadIdx.x;
  int node0 = b << BKT_SHIFT;
  int eb0 = bbase[b];
  int ebn = bcnt[b];
  cnt[tid] = 0;
  __syncthreads();
  for (int i = tid; i < ebn; i += 256) atomicAdd(&cnt[part[eb0 + i] >> 24], 1);
  __syncthreads();
  int v = cnt[tid];
  sc[tid] = v;
  __syncthreads();
  for (int dd = 1; dd < 256; dd <<= 1) {
    int x = (tid >= dd) ? sc[tid - dd] : 0;
    __syncthreads();
    sc[tid] += x;
    __syncthreads();
  }
  int lo = sc[tid] - v;  // exclusive
  cur[tid] = lo;
  int node = node0 + tid;
  if (node < n) {
    off[node] = eb0 + lo;
    end[node] = eb0 + lo + v;
    dis[node] = rsqrtf((float)v + 1.0f);
  }
  __syncthreads();
  for (int i = tid; i < ebn; i += 256) {
    unsigned int u = part[eb0 + i];
    int r = atomicAdd(&cur[u >> 24], 1);
    csr[eb0 + r] = (int)(u & 0xFFFFFFu);
  }
}

// Pre-split W (K x NOUT, f32) into k-step-blocked bf16 hi/lo:
//   Wsp[ks][hl][g][n][8] ; k = ks*32 + g*8 + j
template<int K, int NOUT>
__global__ __launch_bounds__(256) void k_split_w(const float* __restrict__ W,
                                                 __bf16* __restrict__ Wsp) {
  constexpr int KSTEPS = K / 32;
  int idx = blockIdx.x * 256 + threadIdx.x;  // (ks, g, n)
  if (idx >= KSTEPS * 4 * NOUT) return;
  int n = idx % NOUT;
  int g = (idx / NOUT) & 3;
  int ks = idx / (4 * NOUT);
  __bf16* hi = Wsp + (size_t)ks * (2 * 4 * NOUT * 8) + ((size_t)g * NOUT + n) * 8;
  __bf16* lo = hi + 4 * NOUT * 8;
#pragma unroll
  for (int j = 0; j < 8; ++j) {
    float f = W[(size_t)(ks * 32 + g * 8 + j) * NOUT + n];
    __bf16 h = (__bf16)f;
    hi[j] = h;
    lo[j] = (__bf16)(f - (float)h);
  }
}

// MFMA split-bf16 GEMM, barrier-free: T[m] = bf16( dis[m] * (X'[m] @ W) ),
// X' = relu(X+inb) if flagged. BM=128, 4 independent waves x 32 rows.
// B fragments read directly from global (L2-resident Wsp); A reg-prefetch.
template<int K, int NOUT, bool IN_RELU_BIAS>
__global__ __launch_bounds__(256) void k_gemm_mfma(
    const float* __restrict__ X, const __bf16* __restrict__ Wsp,
    const float* __restrict__ inb, const float* __restrict__ dis,
    __bf16* __restrict__ T, int M) {
  constexpr int BM = 128;
  constexpr int NF = NOUT / 16;            // n-frags per wave
  constexpr int KSTEPS = K / 32;
  constexpr int TILE = 2 * 4 * NOUT * 8;   // bf16 elems per kstep (hi+lo)

  const int tid = threadIdx.x;
  const int wave = tid >> 6;
  const int lane = tid & 63;
  const int l15 = lane & 15;
  const int lg = lane >> 4;                 // k-group 0..3
  const int r0w = blockIdx.x * BM + wave * 32;

  f32x4 acc[2][NF];
#pragma unroll
  for (int mf = 0; mf < 2; ++mf)
#pragma unroll
    for (int nf = 0; nf < NF; ++nf) acc[mf][nf] = (f32x4){0.f, 0.f, 0.f, 0.f};

  int rowA[2];
#pragma unroll
  for (int mf = 0; mf < 2; ++mf) {
    int r = r0w + mf * 16 + l15;
    rowA[mf] = (r < M) ? r : (M - 1);  // clamp: OOB rows never stored
  }

  auto loadA = [&](int ks, float4* v0, float4* v1) {
#pragma unroll
    for (int mf = 0; mf < 2; ++mf) {
      const float* ap = X + (size_t)rowA[mf] * K + ks * 32 + lg * 8;
      v0[mf] = *(const float4*)ap;
      v1[mf] = *(const float4*)(ap + 4);
    }
  };

  float4 ca0[2], ca1[2], na0[2], na1[2];
  loadA(0, ca0, ca1);

  const int boff = lg * NOUT * 8 + l15 * 8;
#pragma unroll 1
  for (int ks = 0; ks < KSTEPS; ++ks) {
    if (ks + 1 < KSTEPS) loadA(ks + 1, na0, na1);  // reg prefetch, no barrier
    // ---- split current A (f32 -> bf16 hi/lo), optional relu+bias
    bf16x8 ah[2], al[2];
    const int k0 = ks * 32 + lg * 8;
#pragma unroll
    for (int mf = 0; mf < 2; ++mf) {
      float va[8] = {ca0[mf].x, ca0[mf].y, ca0[mf].z, ca0[mf].w,
                     ca1[mf].x, ca1[mf].y, ca1[mf].z, ca1[mf].w};
      if (IN_RELU_BIAS) {
        float4 bb0 = *(const float4*)(inb + k0);
        float4 bb1 = *(const float4*)(inb + k0 + 4);
        float bb[8] = {bb0.x, bb0.y, bb0.z, bb0.w, bb1.x, bb1.y, bb1.z, bb1.w};
#pragma unroll
        for (int j = 0; j < 8; ++j) va[j] = fmaxf(va[j] + bb[j], 0.f);
      }
#pragma unroll
      for (int j = 0; j < 8; ++j) {
        __bf16 h = (__bf16)va[j];
        ah[mf][j] = h;
        al[mf][j] = (__bf16)(va[j] - (float)h);
      }
    }
    // ---- B fragments direct from global (L2/L1-resident) + MFMA (3-term)
    const __bf16* wk = Wsp + (size_t)ks * TILE;
    const __bf16* wkl = wk + 4 * NOUT * 8;
#pragma unroll
    for (int nf = 0; nf < NF; ++nf) {
      bf16x8 bh = *(const bf16x8*)(wk + boff + nf * 128);
      bf16x8 bl = *(const bf16x8*)(wkl + boff + nf * 128);
#pragma unroll
      for (int mf = 0; mf < 2; ++mf) {
        acc[mf][nf] = __builtin_amdgcn_mfma_f32_16x16x32_bf16(ah[mf], bh, acc[mf][nf], 0, 0, 0);
        acc[mf][nf] = __builtin_amdgcn_mfma_f32_16x16x32_bf16(ah[mf], bl, acc[mf][nf], 0, 0, 0);
        acc[mf][nf] = __builtin_amdgcn_mfma_f32_16x16x32_bf16(al[mf], bh, acc[mf][nf], 0, 0, 0);
      }
    }
#pragma unroll
    for (int mf = 0; mf < 2; ++mf) {
      ca0[mf] = na0[mf];
      ca1[mf] = na1[mf];
    }
  }

  // ---- epilogue: C[col=l15, row=lg*4+r]; T[m] = bf16(dis[m] * acc)
#pragma unroll
  for (int mf = 0; mf < 2; ++mf) {
    int rbase = r0w + mf * 16 + lg * 4;
    float dv[4];
#pragma unroll
    for (int r = 0; r < 4; ++r) dv[r] = (rbase + r < M) ? dis[rbase + r] : 0.f;
#pragma unroll
    for (int nf = 0; nf < NF; ++nf) {
#pragma unroll
      for (int r = 0; r < 4; ++r) {
        int rr = rbase + r;
        if (rr < M) T[(size_t)rr * NOUT + nf * 16 + l15] = (__bf16)(dv[r] * acc[mf][nf][r]);
      }
    }
  }
}

// CSR gather aggregation over bf16 table: wave per node, G lane-groups of LPG
// lanes; each lane loads bf16x8 (16B), accumulates f32; shfl_xor group fold.
// out[i] = dis[i] * (sum ts[s] + ts[i]) (+ bias), written f32.
template<int C, bool BIAS>
__global__ __launch_bounds__(256) void k_agg_csr(
    const int* __restrict__ csr, const int* __restrict__ off,
    const int* __restrict__ end, const __bf16* __restrict__ ts,
    const float* __restrict__ dis, const float* __restrict__ bias,
    float* __restrict__ out, int n) {
  constexpr int LPG = C / 8;   // lanes per group: 16 (C=128), 8 (C=64)
  constexpr int G = 64 / LPG;  // groups per wave: 4, 8
  int wid = (blockIdx.x * 256 + threadIdx.x) >> 6;
  int lane = threadIdx.x & 63;
  int gid = lane / LPG;
  int gl = lane % LPG;
  if (wid >= n) return;

  float acc[8];
#pragma unroll
  for (int j = 0; j < 8; ++j) acc[j] = 0.f;
  if (gid == 0) {  // self term
    bf16x8 v = *(const bf16x8*)(ts + (size_t)wid * C + gl * 8);
#pragma unroll
    for (int j = 0; j < 8; ++j) acc[j] = (float)v[j];
  }

  int e = off[wid] + gid;
  int e1 = end[wid];
  for (; e + G < e1; e += 2 * G) {
    int s0 = csr[e];
    int s1 = csr[e + G];
    bf16x8 v0 = *(const bf16x8*)(ts + (size_t)s0 * C + gl * 8);
    bf16x8 v1 = *(const bf16x8*)(ts + (size_t)s1 * C + gl * 8);
#pragma unroll
    for (int j = 0; j < 8; ++j) acc[j] += (float)v0[j] + (float)v1[j];
  }
  if (e < e1) {
    int s0 = csr[e];
    bf16x8 v0 = *(const bf16x8*)(ts + (size_t)s0 * C + gl * 8);
#pragma unroll
    for (int j = 0; j < 8; ++j) acc[j] += (float)v0[j];
  }

  // cross-group reduce: fold groups down to lanes [0, LPG)
#pragma unroll
  for (int w = LPG; w < 64; w <<= 1) {
#pragma unroll
    for (int j = 0; j < 8; ++j) acc[j] += __shfl_xor(acc[j], w);
  }

  if (gid == 0) {
    float di = dis[wid];
    float o[8];
#pragma unroll
    for (int j = 0; j < 8; ++j) {
      o[j] = di * acc[j];
      if (BIAS) o[j] += bias[gl * 8 + j];
    }
    float4* op = (float4*)(out + (size_t)wid * C + gl * 8);
    op[0] = make_float4(o[0], o[1], o[2], o[3]);
    op[1] = make_float4(o[4], o[5], o[6], o[7]);
  }
}

extern "C" void kernel_launch(void* const* d_in, const int* in_sizes, int n_in,
                              void* d_out, int out_size, void* d_ws, size_t ws_size,
                              hipStream_t stream) {
  const float* x  = (const float*)d_in[0];
  const int*   ei = (const int*)d_in[1];
  const float* W1 = (const float*)d_in[2];
  const float* b1 = (const float*)d_in[3];
  const float* W2 = (const float*)d_in[4];
  const float* b2 = (const float*)d_in[5];
  float* out = (float*)d_out;

  const int N = in_sizes[0] / GCN_IN_C;  // 100000
  const int E = in_sizes[1] / 2;         // 1600000
  const int* src = ei;
  const int* dst = ei + E;
  const int NB = (N + BKT_NODES - 1) >> BKT_SHIFT;  // 391 buckets
  const int EB = (E + EPB - 1) / EPB;               // partition blocks

  // ws layout:
  //   dis[N] | t1s(bf16)[N*128] | a1(f32)[N*128] | off[N] | end[N] | csr[E]
  //   | bcnt|bbase|bcur [512 each] | w1sp | w2sp
  //   part[E] aliases a1 (dead before agg1 writes a1)
  char* p = (char*)d_ws;
  float* dis = (float*)p;             p += (size_t)N * 4;
  __bf16* t1s = (__bf16*)p;           p += (size_t)N * GCN_HID * 2;
  float* a1  = (float*)p;             p += (size_t)N * GCN_HID * 4;
  int* off   = (int*)p;               p += (size_t)N * 4;
  int* end   = (int*)p;               p += (size_t)N * 4;
  int* csr   = (int*)p;               p += (size_t)E * 4;
  int* bcnt  = (int*)p;               p += 512 * 4;
  int* bbase = (int*)p;               p += 512 * 4;
  int* bcur  = (int*)p;               p += 512 * 4;
  __bf16* w1sp = (__bf16*)p;          p += (size_t)(GCN_IN_C / 32) * 2 * 4 * GCN_HID * 8 * 2;
  __bf16* w2sp = (__bf16*)p;
  unsigned int* part = (unsigned int*)a1;  // alias
  __bf16* t2s = t1s;  // layer-2 table reuses layer-1 table (row stride 64)

  // ---- weight pre-split (bf16 hi/lo, k-step-blocked)
  k_split_w<GCN_IN_C, GCN_HID>
      <<<((GCN_IN_C / 32) * 4 * GCN_HID + 255) / 256, 256, 0, stream>>>(W1, w1sp);
  k_split_w<GCN_HID, GCN_OUT>
      <<<((GCN_HID / 32) * 4 * GCN_OUT + 255) / 256, 256, 0, stream>>>(W2, w2sp);

  // ---- CSR build (bucketed counting sort)
  k_zero_i32<<<2, 256, 0, stream>>>(bcnt, 512);
  k_bucket_hist<<<EB, 256, 0, stream>>>(dst, bcnt, E, NB);
  k_scan_buckets<<<1, 512, 0, stream>>>(bcnt, bbase, bcur, NB);
  k_partition<<<EB, 256, 0, stream>>>(src, dst, bcur, part, E, NB);
  k_bucket_csr<<<NB, 256, 0, stream>>>(part, bbase, bcnt, off, end, dis, csr, N);

  // ---- layer 1
  k_gemm_mfma<GCN_IN_C, GCN_HID, false>
      <<<(N + 127) / 128, 256, 0, stream>>>(x, w1sp, nullptr, dis, t1s, N);
  k_agg_csr<GCN_HID, false>
      <<<((size_t)N * 64 + 255) / 256, 256, 0, stream>>>(csr, off, end, t1s, dis, nullptr, a1, N);

  // ---- layer 2
  k_gemm_mfma<GCN_HID, GCN_OUT, true>
      <<<(N + 127) / 128, 256, 0, stream>>>(a1, w2sp, b1, dis, t2s, N);
  k_agg_csr<GCN_OUT, true>
      <<<((size_t)N * 64 + 255) / 256, 256, 0, stream>>>(csr, off, end, t2s, dis, b2, out, N);
}

// Round 10
// 243.011 us; speedup vs baseline: 1.0182x; 1.0182x over previous
//
#include <hip/hip_runtime.h>
#include <hip/hip_bf16.h>

// GCN encoder: out = GCNconv2( relu(GCNconv1(x)) )
// GCNconv(h,W,b) = D^-1/2 (A+I) D^-1/2 (h W) + b
//
// R9: occupancy + epilogue fix for the MFMA GEMM.
//   - mf=1: 16 rows/wave, BM=64 -> 2x grid (1564 blocks), launch_bounds(256,5)
//   - swapped MFMA operands (W-frag as A-op, X-frag as B-op) -> lane holds
//     4 consecutive out-cols of one row -> packed 8B epilogue stores
//   - barrier-free: B direct from L2-resident Wsp, A reg-prefetch 1 ahead
//   CSR build + bf16 gather agg unchanged from R6.

#define GCN_IN_C 256
#define GCN_HID  128
#define GCN_OUT  64

#define BKT_SHIFT 8
#define BKT_NODES 256
#define EPB 4096  // edges per block in partition kernels

typedef __bf16 bf16x8 __attribute__((ext_vector_type(8)));
typedef __bf16 bf16x4 __attribute__((ext_vector_type(4)));
typedef float f32x4 __attribute__((ext_vector_type(4)));

__global__ __launch_bounds__(256) void k_zero_i32(int* __restrict__ p, int n) {
  int i = blockIdx.x * 256 + threadIdx.x;
  if (i < n) p[i] = 0;
}

// P1a: bucket sizes
__global__ __launch_bounds__(256) void k_bucket_hist(const int* __restrict__ dst,
                                                     int* __restrict__ bcnt, int e, int nb) {
  __shared__ int h[512];
  int tid = threadIdx.x;
  h[tid] = 0; h[tid + 256] = 0;
  __syncthreads();
  int base = blockIdx.x * EPB;
#pragma unroll
  for (int j = 0; j < EPB / 256; ++j) {
    int i = base + j * 256 + tid;
    if (i < e) atomicAdd(&h[dst[i] >> BKT_SHIFT], 1);
  }
  __syncthreads();
  if (tid < nb && h[tid]) atomicAdd(&bcnt[tid], h[tid]);
  if (tid + 256 < nb && h[tid + 256]) atomicAdd(&bcnt[tid + 256], h[tid + 256]);
}

// exclusive scan of bucket sizes (nb <= 512), writes bbase and bcur
__global__ __launch_bounds__(512) void k_scan_buckets(const int* __restrict__ bcnt,
                                                      int* __restrict__ bbase,
                                                      int* __restrict__ bcur, int nb) {
  __shared__ int sh[512];
  int t = threadIdx.x;
  int v = (t < nb) ? bcnt[t] : 0;
  sh[t] = v;
  __syncthreads();
  for (int d = 1; d < 512; d <<= 1) {
    int x = (t >= d) ? sh[t - d] : 0;
    __syncthreads();
    sh[t] += x;
    __syncthreads();
  }
  if (t < nb) {
    int ex = sh[t] - v;
    bbase[t] = ex;
    bcur[t] = ex;
  }
}

// P1b: partition edges into bucket-contiguous regions (packed 4B)
__global__ __launch_bounds__(256) void k_partition(const int* __restrict__ src,
                                                   const int* __restrict__ dst,
                                                   int* __restrict__ bcur,
                                                   unsigned int* __restrict__ part,
                                                   int e, int nb) {
  __shared__ int h[512];
  __shared__ int base[512];
  int tid = threadIdx.x;
  h[tid] = 0; h[tid + 256] = 0;
  __syncthreads();
  int b0 = blockIdx.x * EPB;
  int s[EPB / 256], d[EPB / 256], rk[EPB / 256];
#pragma unroll
  for (int j = 0; j < EPB / 256; ++j) {
    int i = b0 + j * 256 + tid;
    if (i < e) {
      s[j] = src[i];
      d[j] = dst[i];
      rk[j] = atomicAdd(&h[d[j] >> BKT_SHIFT], 1);
    }
  }
  __syncthreads();
  if (tid < nb && h[tid]) base[tid] = atomicAdd(&bcur[tid], h[tid]);
  if (tid + 256 < nb && h[tid + 256]) base[tid + 256] = atomicAdd(&bcur[tid + 256], h[tid + 256]);
  __syncthreads();
#pragma unroll
  for (int j = 0; j < EPB / 256; ++j) {
    int i = b0 + j * 256 + tid;
    if (i < e) {
      int bk = d[j] >> BKT_SHIFT;
      unsigned int dl = (unsigned int)(d[j] & (BKT_NODES - 1));
      part[base[bk] + rk[j]] = (dl << 24) | (unsigned int)s[j];
    }
  }
}

// P2: per-bucket CSR finalize. One block per bucket.
__global__ __launch_bounds__(256) void k_bucket_csr(
    const unsigned int* __restrict__ part, const int* __restrict__ bbase,
    const int* __restrict__ bcnt, int* __restrict__ off, int* __restrict__ end,
    float* __restrict__ dis, int* __restrict__ csr, int n) {
  __shared__ int cnt[256];
  __shared__ int sc[256];
  __shared__ int cur[256];
  int b = blockIdx.x, tid = threadIdx.x;
  int node0 = b << BKT_SHIFT;
  int eb0 = bbase[b];
  int ebn = bcnt[b];
  cnt[tid] = 0;
  __syncthreads();
  for (int i = tid; i < ebn; i += 256) atomicAdd(&cnt[part[eb0 + i] >> 24], 1);
  __syncthreads();
  int v = cnt[tid];
  sc[tid] = v;
  __syncthreads();
  for (int dd = 1; dd < 256; dd <<= 1) {
    int x = (tid >= dd) ? sc[tid - dd] : 0;
    __syncthreads();
    sc[tid] += x;
    __syncthreads();
  }
  int lo = sc[tid] - v;  // exclusive
  cur[tid] = lo;
  int node = node0 + tid;
  if (node < n) {
    off[node] = eb0 + lo;
    end[node] = eb0 + lo + v;
    dis[node] = rsqrtf((float)v + 1.0f);
  }
  __syncthreads();
  for (int i = tid; i < ebn; i += 256) {
    unsigned int u = part[eb0 + i];
    int r = atomicAdd(&cur[u >> 24], 1);
    csr[eb0 + r] = (int)(u & 0xFFFFFFu);
  }
}

// Pre-split W (K x NOUT, f32) into k-step-blocked bf16 hi/lo:
//   Wsp[ks][hl][g][n][8] ; k = ks*32 + g*8 + j
template<int K, int NOUT>
__global__ __launch_bounds__(256) void k_split_w(const float* __restrict__ W,
                                                 __bf16* __restrict__ Wsp) {
  constexpr int KSTEPS = K / 32;
  int idx = blockIdx.x * 256 + threadIdx.x;  // (ks, g, n)
  if (idx >= KSTEPS * 4 * NOUT) return;
  int n = idx % NOUT;
  int g = (idx / NOUT) & 3;
  int ks = idx / (4 * NOUT);
  __bf16* hi = Wsp + (size_t)ks * (2 * 4 * NOUT * 8) + ((size_t)g * NOUT + n) * 8;
  __bf16* lo = hi + 4 * NOUT * 8;
#pragma unroll
  for (int j = 0; j < 8; ++j) {
    float f = W[(size_t)(ks * 32 + g * 8 + j) * NOUT + n];
    __bf16 h = (__bf16)f;
    hi[j] = h;
    lo[j] = (__bf16)(f - (float)h);
  }
}

// MFMA split-bf16 GEMM, barrier-free, swapped operands.
// T[m] = bf16( dis[m] * (X'[m] @ W) ), X' = relu(X+inb) if flagged.
// BM=64, 4 waves x 16 rows. D' = Wfrag^T * Xfrag: lane(l15,lg) holds, per nf,
// rows of T = r0w+l15 and cols nf*16+lg*4+(0..3) -> packed 8B stores.
template<int K, int NOUT, bool IN_RELU_BIAS>
__global__ __launch_bounds__(256, 5) void k_gemm_mfma(
    const float* __restrict__ X, const __bf16* __restrict__ Wsp,
    const float* __restrict__ inb, const float* __restrict__ dis,
    __bf16* __restrict__ T, int M) {
  constexpr int BM = 64;
  constexpr int NF = NOUT / 16;            // n-frags per wave
  constexpr int KSTEPS = K / 32;
  constexpr int TILE = 2 * 4 * NOUT * 8;   // bf16 elems per kstep (hi+lo)

  const int tid = threadIdx.x;
  const int wave = tid >> 6;
  const int lane = tid & 63;
  const int l15 = lane & 15;
  const int lg = lane >> 4;                 // k-group 0..3
  const int r0w = blockIdx.x * BM + wave * 16;

  f32x4 acc[NF];
#pragma unroll
  for (int nf = 0; nf < NF; ++nf) acc[nf] = (f32x4){0.f, 0.f, 0.f, 0.f};

  int row = r0w + l15;
  int rowA = (row < M) ? row : (M - 1);  // clamp: OOB rows never stored

  auto loadA = [&](int ks, float4* v0, float4* v1) {
    const float* ap = X + (size_t)rowA * K + ks * 32 + lg * 8;
    *v0 = *(const float4*)ap;
    *v1 = *(const float4*)(ap + 4);
  };

  float4 ca0, ca1, na0, na1;
  loadA(0, &ca0, &ca1);

  const int boff = lg * NOUT * 8 + l15 * 8;
#pragma unroll 1
  for (int ks = 0; ks < KSTEPS; ++ks) {
    if (ks + 1 < KSTEPS) loadA(ks + 1, &na0, &na1);  // reg prefetch
    // ---- split current A (f32 -> bf16 hi/lo), optional relu+bias
    bf16x8 ah, al;
    const int k0 = ks * 32 + lg * 8;
    {
      float va[8] = {ca0.x, ca0.y, ca0.z, ca0.w, ca1.x, ca1.y, ca1.z, ca1.w};
      if (IN_RELU_BIAS) {
        float4 bb0 = *(const float4*)(inb + k0);
        float4 bb1 = *(const float4*)(inb + k0 + 4);
        float bb[8] = {bb0.x, bb0.y, bb0.z, bb0.w, bb1.x, bb1.y, bb1.z, bb1.w};
#pragma unroll
        for (int j = 0; j < 8; ++j) va[j] = fmaxf(va[j] + bb[j], 0.f);
      }
#pragma unroll
      for (int j = 0; j < 8; ++j) {
        __bf16 h = (__bf16)va[j];
        ah[j] = h;
        al[j] = (__bf16)(va[j] - (float)h);
      }
    }
    // ---- B fragments direct from global + MFMA, SWAPPED operands:
    //      acc = mfma(Wfrag, Xfrag, acc) -> D[wcol][xrow]
    const __bf16* wk = Wsp + (size_t)ks * TILE;
    const __bf16* wkl = wk + 4 * NOUT * 8;
#pragma unroll
    for (int nf = 0; nf < NF; ++nf) {
      bf16x8 bh = *(const bf16x8*)(wk + boff + nf * 128);
      bf16x8 bl = *(const bf16x8*)(wkl + boff + nf * 128);
      acc[nf] = __builtin_amdgcn_mfma_f32_16x16x32_bf16(bh, ah, acc[nf], 0, 0, 0);
      acc[nf] = __builtin_amdgcn_mfma_f32_16x16x32_bf16(bl, ah, acc[nf], 0, 0, 0);
      acc[nf] = __builtin_amdgcn_mfma_f32_16x16x32_bf16(bh, al, acc[nf], 0, 0, 0);
    }
    ca0 = na0;
    ca1 = na1;
  }

  // ---- epilogue: lane holds T[row][nf*16 + lg*4 + r], r=0..3 -> 8B stores
  if (row < M) {
    float dv = dis[row];
#pragma unroll
    for (int nf = 0; nf < NF; ++nf) {
      bf16x4 pk;
#pragma unroll
      for (int r = 0; r < 4; ++r) pk[r] = (__bf16)(dv * acc[nf][r]);
      *(bf16x4*)(T + (size_t)row * NOUT + nf * 16 + lg * 4) = pk;
    }
  }
}

// CSR gather aggregation over bf16 table: wave per node, G lane-groups of LPG
// lanes; each lane loads bf16x8 (16B), accumulates f32; shfl_xor group fold.
// out[i] = dis[i] * (sum ts[s] + ts[i]) (+ bias), written f32.
template<int C, bool BIAS>
__global__ __launch_bounds__(256) void k_agg_csr(
    const int* __restrict__ csr, const int* __restrict__ off,
    const int* __restrict__ end, const __bf16* __restrict__ ts,
    const float* __restrict__ dis, const float* __restrict__ bias,
    float* __restrict__ out, int n) {
  constexpr int LPG = C / 8;   // lanes per group: 16 (C=128), 8 (C=64)
  constexpr int G = 64 / LPG;  // groups per wave: 4, 8
  int wid = (blockIdx.x * 256 + threadIdx.x) >> 6;
  int lane = threadIdx.x & 63;
  int gid = lane / LPG;
  int gl = lane % LPG;
  if (wid >= n) return;

  float acc[8];
#pragma unroll
  for (int j = 0; j < 8; ++j) acc[j] = 0.f;
  if (gid == 0) {  // self term
    bf16x8 v = *(const bf16x8*)(ts + (size_t)wid * C + gl * 8);
#pragma unroll
    for (int j = 0; j < 8; ++j) acc[j] = (float)v[j];
  }

  int e = off[wid] + gid;
  int e1 = end[wid];
  for (; e + G < e1; e += 2 * G) {
    int s0 = csr[e];
    int s1 = csr[e + G];
    bf16x8 v0 = *(const bf16x8*)(ts + (size_t)s0 * C + gl * 8);
    bf16x8 v1 = *(const bf16x8*)(ts + (size_t)s1 * C + gl * 8);
#pragma unroll
    for (int j = 0; j < 8; ++j) acc[j] += (float)v0[j] + (float)v1[j];
  }
  if (e < e1) {
    int s0 = csr[e];
    bf16x8 v0 = *(const bf16x8*)(ts + (size_t)s0 * C + gl * 8);
#pragma unroll
    for (int j = 0; j < 8; ++j) acc[j] += (float)v0[j];
  }

  // cross-group reduce: fold groups down to lanes [0, LPG)
#pragma unroll
  for (int w = LPG; w < 64; w <<= 1) {
#pragma unroll
    for (int j = 0; j < 8; ++j) acc[j] += __shfl_xor(acc[j], w);
  }

  if (gid == 0) {
    float di = dis[wid];
    float o[8];
#pragma unroll
    for (int j = 0; j < 8; ++j) {
      o[j] = di * acc[j];
      if (BIAS) o[j] += bias[gl * 8 + j];
    }
    float4* op = (float4*)(out + (size_t)wid * C + gl * 8);
    op[0] = make_float4(o[0], o[1], o[2], o[3]);
    op[1] = make_float4(o[4], o[5], o[6], o[7]);
  }
}

extern "C" void kernel_launch(void* const* d_in, const int* in_sizes, int n_in,
                              void* d_out, int out_size, void* d_ws, size_t ws_size,
                              hipStream_t stream) {
  const float* x  = (const float*)d_in[0];
  const int*   ei = (const int*)d_in[1];
  const float* W1 = (const float*)d_in[2];
  const float* b1 = (const float*)d_in[3];
  const float* W2 = (const float*)d_in[4];
  const float* b2 = (const float*)d_in[5];
  float* out = (float*)d_out;

  const int N = in_sizes[0] / GCN_IN_C;  // 100000
  const int E = in_sizes[1] / 2;         // 1600000
  const int* src = ei;
  const int* dst = ei + E;
  const int NB = (N + BKT_NODES - 1) >> BKT_SHIFT;  // 391 buckets
  const int EB = (E + EPB - 1) / EPB;               // partition blocks

  // ws layout:
  //   dis[N] | t1s(bf16)[N*128] | a1(f32)[N*128] | off[N] | end[N] | csr[E]
  //   | bcnt|bbase|bcur [512 each] | w1sp | w2sp
  //   part[E] aliases a1 (dead before agg1 writes a1)
  char* p = (char*)d_ws;
  float* dis = (float*)p;             p += (size_t)N * 4;
  __bf16* t1s = (__bf16*)p;           p += (size_t)N * GCN_HID * 2;
  float* a1  = (float*)p;             p += (size_t)N * GCN_HID * 4;
  int* off   = (int*)p;               p += (size_t)N * 4;
  int* end   = (int*)p;               p += (size_t)N * 4;
  int* csr   = (int*)p;               p += (size_t)E * 4;
  int* bcnt  = (int*)p;               p += 512 * 4;
  int* bbase = (int*)p;               p += 512 * 4;
  int* bcur  = (int*)p;               p += 512 * 4;
  __bf16* w1sp = (__bf16*)p;          p += (size_t)(GCN_IN_C / 32) * 2 * 4 * GCN_HID * 8 * 2;
  __bf16* w2sp = (__bf16*)p;
  unsigned int* part = (unsigned int*)a1;  // alias
  __bf16* t2s = t1s;  // layer-2 table reuses layer-1 table (row stride 64)

  // ---- weight pre-split (bf16 hi/lo, k-step-blocked)
  k_split_w<GCN_IN_C, GCN_HID>
      <<<((GCN_IN_C / 32) * 4 * GCN_HID + 255) / 256, 256, 0, stream>>>(W1, w1sp);
  k_split_w<GCN_HID, GCN_OUT>
      <<<((GCN_HID / 32) * 4 * GCN_OUT + 255) / 256, 256, 0, stream>>>(W2, w2sp);

  // ---- CSR build (bucketed counting sort)
  k_zero_i32<<<2, 256, 0, stream>>>(bcnt, 512);
  k_bucket_hist<<<EB, 256, 0, stream>>>(dst, bcnt, E, NB);
  k_scan_buckets<<<1, 512, 0, stream>>>(bcnt, bbase, bcur, NB);
  k_partition<<<EB, 256, 0, stream>>>(src, dst, bcur, part, E, NB);
  k_bucket_csr<<<NB, 256, 0, stream>>>(part, bbase, bcnt, off, end, dis, csr, N);

  // ---- layer 1
  k_gemm_mfma<GCN_IN_C, GCN_HID, false>
      <<<(N + 63) / 64, 256, 0, stream>>>(x, w1sp, nullptr, dis, t1s, N);
  k_agg_csr<GCN_HID, false>
      <<<((size_t)N * 64 + 255) / 256, 256, 0, stream>>>(csr, off, end, t1s, dis, nullptr, a1, N);

  // ---- layer 2
  k_gemm_mfma<GCN_HID, GCN_OUT, true>
      <<<(N + 63) / 64, 256, 0, stream>>>(a1, w2sp, b1, dis, t2s, N);
  k_agg_csr<GCN_OUT, true>
      <<<((size_t)N * 64 + 255) / 256, 256, 0, stream>>>(csr, off, end, t2s, dis, b2, out, N);
}

// Round 11
// 241.729 us; speedup vs baseline: 1.0236x; 1.0053x over previous
//
#include <hip/hip_runtime.h>
#include <hip/hip_bf16.h>

// GCN encoder: out = GCNconv2( relu(GCNconv1(x)) )
// GCNconv(h,W,b) = D^-1/2 (A+I) D^-1/2 (h W) + b
//
// R10: byte-diet + deeper MLP.
//   - agg1 epilogue: a1' = relu(dis*sum + b1) stored bf16 (halves a1 traffic)
//   - gemm2: plain 2-term bf16 GEMM (A exact bf16, no split, no bias)
//   - aggs: 4-deep edge unroll (16 gathers in flight/wave)
//   gemm1 (split-bf16, swapped-operand, barrier-free) unchanged from R9.

#define GCN_IN_C 256
#define GCN_HID  128
#define GCN_OUT  64

#define BKT_SHIFT 8
#define BKT_NODES 256
#define EPB 4096  // edges per block in partition kernels

typedef __bf16 bf16x8 __attribute__((ext_vector_type(8)));
typedef __bf16 bf16x4 __attribute__((ext_vector_type(4)));
typedef float f32x4 __attribute__((ext_vector_type(4)));

__global__ __launch_bounds__(256) void k_zero_i32(int* __restrict__ p, int n) {
  int i = blockIdx.x * 256 + threadIdx.x;
  if (i < n) p[i] = 0;
}

// P1a: bucket sizes
__global__ __launch_bounds__(256) void k_bucket_hist(const int* __restrict__ dst,
                                                     int* __restrict__ bcnt, int e, int nb) {
  __shared__ int h[512];
  int tid = threadIdx.x;
  h[tid] = 0; h[tid + 256] = 0;
  __syncthreads();
  int base = blockIdx.x * EPB;
#pragma unroll
  for (int j = 0; j < EPB / 256; ++j) {
    int i = base + j * 256 + tid;
    if (i < e) atomicAdd(&h[dst[i] >> BKT_SHIFT], 1);
  }
  __syncthreads();
  if (tid < nb && h[tid]) atomicAdd(&bcnt[tid], h[tid]);
  if (tid + 256 < nb && h[tid + 256]) atomicAdd(&bcnt[tid + 256], h[tid + 256]);
}

// exclusive scan of bucket sizes (nb <= 512), writes bbase and bcur
__global__ __launch_bounds__(512) void k_scan_buckets(const int* __restrict__ bcnt,
                                                      int* __restrict__ bbase,
                                                      int* __restrict__ bcur, int nb) {
  __shared__ int sh[512];
  int t = threadIdx.x;
  int v = (t < nb) ? bcnt[t] : 0;
  sh[t] = v;
  __syncthreads();
  for (int d = 1; d < 512; d <<= 1) {
    int x = (t >= d) ? sh[t - d] : 0;
    __syncthreads();
    sh[t] += x;
    __syncthreads();
  }
  if (t < nb) {
    int ex = sh[t] - v;
    bbase[t] = ex;
    bcur[t] = ex;
  }
}

// P1b: partition edges into bucket-contiguous regions (packed 4B)
__global__ __launch_bounds__(256) void k_partition(const int* __restrict__ src,
                                                   const int* __restrict__ dst,
                                                   int* __restrict__ bcur,
                                                   unsigned int* __restrict__ part,
                                                   int e, int nb) {
  __shared__ int h[512];
  __shared__ int base[512];
  int tid = threadIdx.x;
  h[tid] = 0; h[tid + 256] = 0;
  __syncthreads();
  int b0 = blockIdx.x * EPB;
  int s[EPB / 256], d[EPB / 256], rk[EPB / 256];
#pragma unroll
  for (int j = 0; j < EPB / 256; ++j) {
    int i = b0 + j * 256 + tid;
    if (i < e) {
      s[j] = src[i];
      d[j] = dst[i];
      rk[j] = atomicAdd(&h[d[j] >> BKT_SHIFT], 1);
    }
  }
  __syncthreads();
  if (tid < nb && h[tid]) base[tid] = atomicAdd(&bcur[tid], h[tid]);
  if (tid + 256 < nb && h[tid + 256]) base[tid + 256] = atomicAdd(&bcur[tid + 256], h[tid + 256]);
  __syncthreads();
#pragma unroll
  for (int j = 0; j < EPB / 256; ++j) {
    int i = b0 + j * 256 + tid;
    if (i < e) {
      int bk = d[j] >> BKT_SHIFT;
      unsigned int dl = (unsigned int)(d[j] & (BKT_NODES - 1));
      part[base[bk] + rk[j]] = (dl << 24) | (unsigned int)s[j];
    }
  }
}

// P2: per-bucket CSR finalize. One block per bucket.
__global__ __launch_bounds__(256) void k_bucket_csr(
    const unsigned int* __restrict__ part, const int* __restrict__ bbase,
    const int* __restrict__ bcnt, int* __restrict__ off, int* __restrict__ end,
    float* __restrict__ dis, int* __restrict__ csr, int n) {
  __shared__ int cnt[256];
  __shared__ int sc[256];
  __shared__ int cur[256];
  int b = blockIdx.x, tid = threadIdx.x;
  int node0 = b << BKT_SHIFT;
  int eb0 = bbase[b];
  int ebn = bcnt[b];
  cnt[tid] = 0;
  __syncthreads();
  for (int i = tid; i < ebn; i += 256) atomicAdd(&cnt[part[eb0 + i] >> 24], 1);
  __syncthreads();
  int v = cnt[tid];
  sc[tid] = v;
  __syncthreads();
  for (int dd = 1; dd < 256; dd <<= 1) {
    int x = (tid >= dd) ? sc[tid - dd] : 0;
    __syncthreads();
    sc[tid] += x;
    __syncthreads();
  }
  int lo = sc[tid] - v;  // exclusive
  cur[tid] = lo;
  int node = node0 + tid;
  if (node < n) {
    off[node] = eb0 + lo;
    end[node] = eb0 + lo + v;
    dis[node] = rsqrtf((float)v + 1.0f);
  }
  __syncthreads();
  for (int i = tid; i < ebn; i += 256) {
    unsigned int u = part[eb0 + i];
    int r = atomicAdd(&cur[u >> 24], 1);
    csr[eb0 + r] = (int)(u & 0xFFFFFFu);
  }
}

// Pre-split W (K x NOUT, f32) into k-step-blocked bf16 hi/lo:
//   Wsp[ks][hl][g][n][8] ; k = ks*32 + g*8 + j
template<int K, int NOUT>
__global__ __launch_bounds__(256) void k_split_w(const float* __restrict__ W,
                                                 __bf16* __restrict__ Wsp) {
  constexpr int KSTEPS = K / 32;
  int idx = blockIdx.x * 256 + threadIdx.x;  // (ks, g, n)
  if (idx >= KSTEPS * 4 * NOUT) return;
  int n = idx % NOUT;
  int g = (idx / NOUT) & 3;
  int ks = idx / (4 * NOUT);
  __bf16* hi = Wsp + (size_t)ks * (2 * 4 * NOUT * 8) + ((size_t)g * NOUT + n) * 8;
  __bf16* lo = hi + 4 * NOUT * 8;
#pragma unroll
  for (int j = 0; j < 8; ++j) {
    float f = W[(size_t)(ks * 32 + g * 8 + j) * NOUT + n];
    __bf16 h = (__bf16)f;
    hi[j] = h;
    lo[j] = (__bf16)(f - (float)h);
  }
}

// Layer-1 GEMM: split-bf16 3-term, barrier-free, swapped operands.
// T[m] = bf16( dis[m] * (X[m] @ W) ). BM=64, 4 waves x 16 rows.
template<int K, int NOUT>
__global__ __launch_bounds__(256, 5) void k_gemm_mfma(
    const float* __restrict__ X, const __bf16* __restrict__ Wsp,
    const float* __restrict__ dis, __bf16* __restrict__ T, int M) {
  constexpr int BM = 64;
  constexpr int NF = NOUT / 16;
  constexpr int KSTEPS = K / 32;
  constexpr int TILE = 2 * 4 * NOUT * 8;

  const int tid = threadIdx.x;
  const int wave = tid >> 6;
  const int lane = tid & 63;
  const int l15 = lane & 15;
  const int lg = lane >> 4;
  const int r0w = blockIdx.x * BM + wave * 16;

  f32x4 acc[NF];
#pragma unroll
  for (int nf = 0; nf < NF; ++nf) acc[nf] = (f32x4){0.f, 0.f, 0.f, 0.f};

  int row = r0w + l15;
  int rowA = (row < M) ? row : (M - 1);

  auto loadA = [&](int ks, float4* v0, float4* v1) {
    const float* ap = X + (size_t)rowA * K + ks * 32 + lg * 8;
    *v0 = *(const float4*)ap;
    *v1 = *(const float4*)(ap + 4);
  };

  float4 ca0, ca1, na0, na1;
  loadA(0, &ca0, &ca1);

  const int boff = lg * NOUT * 8 + l15 * 8;
#pragma unroll 1
  for (int ks = 0; ks < KSTEPS; ++ks) {
    if (ks + 1 < KSTEPS) loadA(ks + 1, &na0, &na1);
    bf16x8 ah, al;
    {
      float va[8] = {ca0.x, ca0.y, ca0.z, ca0.w, ca1.x, ca1.y, ca1.z, ca1.w};
#pragma unroll
      for (int j = 0; j < 8; ++j) {
        __bf16 h = (__bf16)va[j];
        ah[j] = h;
        al[j] = (__bf16)(va[j] - (float)h);
      }
    }
    const __bf16* wk = Wsp + (size_t)ks * TILE;
    const __bf16* wkl = wk + 4 * NOUT * 8;
#pragma unroll
    for (int nf = 0; nf < NF; ++nf) {
      bf16x8 bh = *(const bf16x8*)(wk + boff + nf * 128);
      bf16x8 bl = *(const bf16x8*)(wkl + boff + nf * 128);
      acc[nf] = __builtin_amdgcn_mfma_f32_16x16x32_bf16(bh, ah, acc[nf], 0, 0, 0);
      acc[nf] = __builtin_amdgcn_mfma_f32_16x16x32_bf16(bl, ah, acc[nf], 0, 0, 0);
      acc[nf] = __builtin_amdgcn_mfma_f32_16x16x32_bf16(bh, al, acc[nf], 0, 0, 0);
    }
    ca0 = na0;
    ca1 = na1;
  }

  if (row < M) {
    float dv = dis[row];
#pragma unroll
    for (int nf = 0; nf < NF; ++nf) {
      bf16x4 pk;
#pragma unroll
      for (int r = 0; r < 4; ++r) pk[r] = (__bf16)(dv * acc[nf][r]);
      *(bf16x4*)(T + (size_t)row * NOUT + nf * 16 + lg * 4) = pk;
    }
  }
}

// Layer-2 GEMM: A already bf16 (exact), 2-term MFMA, barrier-free, swapped.
// T[m] = bf16( dis[m] * (A[m] @ W) ). BM=64, 4 waves x 16 rows.
template<int K, int NOUT>
__global__ __launch_bounds__(256) void k_gemm_bf16A(
    const __bf16* __restrict__ A, const __bf16* __restrict__ Wsp,
    const float* __restrict__ dis, __bf16* __restrict__ T, int M) {
  constexpr int BM = 64;
  constexpr int NF = NOUT / 16;
  constexpr int KSTEPS = K / 32;
  constexpr int TILE = 2 * 4 * NOUT * 8;

  const int tid = threadIdx.x;
  const int wave = tid >> 6;
  const int lane = tid & 63;
  const int l15 = lane & 15;
  const int lg = lane >> 4;
  const int r0w = blockIdx.x * BM + wave * 16;

  f32x4 acc[NF];
#pragma unroll
  for (int nf = 0; nf < NF; ++nf) acc[nf] = (f32x4){0.f, 0.f, 0.f, 0.f};

  int row = r0w + l15;
  int rowA = (row < M) ? row : (M - 1);

  bf16x8 ca, na;
  ca = *(const bf16x8*)(A + (size_t)rowA * K + lg * 8);

  const int boff = lg * NOUT * 8 + l15 * 8;
#pragma unroll 1
  for (int ks = 0; ks < KSTEPS; ++ks) {
    if (ks + 1 < KSTEPS)
      na = *(const bf16x8*)(A + (size_t)rowA * K + (ks + 1) * 32 + lg * 8);
    const __bf16* wk = Wsp + (size_t)ks * TILE;
    const __bf16* wkl = wk + 4 * NOUT * 8;
#pragma unroll
    for (int nf = 0; nf < NF; ++nf) {
      bf16x8 bh = *(const bf16x8*)(wk + boff + nf * 128);
      bf16x8 bl = *(const bf16x8*)(wkl + boff + nf * 128);
      acc[nf] = __builtin_amdgcn_mfma_f32_16x16x32_bf16(bh, ca, acc[nf], 0, 0, 0);
      acc[nf] = __builtin_amdgcn_mfma_f32_16x16x32_bf16(bl, ca, acc[nf], 0, 0, 0);
    }
    ca = na;
  }

  if (row < M) {
    float dv = dis[row];
#pragma unroll
    for (int nf = 0; nf < NF; ++nf) {
      bf16x4 pk;
#pragma unroll
      for (int r = 0; r < 4; ++r) pk[r] = (__bf16)(dv * acc[nf][r]);
      *(bf16x4*)(T + (size_t)row * NOUT + nf * 16 + lg * 4) = pk;
    }
  }
}

// CSR gather aggregation over bf16 table: wave per node, G lane-groups of LPG
// lanes; lane loads bf16x8 (16B), accumulates f32, 4-deep unroll; shfl fold.
// o = dis[i]*sum + bias; if RELU o=max(o,0); store OutT (bf16x8 or 2xfloat4).
template<int C, bool RELU, typename OutT>
__global__ __launch_bounds__(256) void k_agg_csr(
    const int* __restrict__ csr, const int* __restrict__ off,
    const int* __restrict__ end, const __bf16* __restrict__ ts,
    const float* __restrict__ dis, const float* __restrict__ bias,
    OutT* __restrict__ out, int n) {
  constexpr int LPG = C / 8;   // lanes per group: 16 (C=128), 8 (C=64)
  constexpr int G = 64 / LPG;  // groups per wave: 4, 8
  int wid = (blockIdx.x * 256 + threadIdx.x) >> 6;
  int lane = threadIdx.x & 63;
  int gid = lane / LPG;
  int gl = lane % LPG;
  if (wid >= n) return;

  float acc[8];
#pragma unroll
  for (int j = 0; j < 8; ++j) acc[j] = 0.f;
  if (gid == 0) {  // self term
    bf16x8 v = *(const bf16x8*)(ts + (size_t)wid * C + gl * 8);
#pragma unroll
    for (int j = 0; j < 8; ++j) acc[j] = (float)v[j];
  }

  int e = off[wid] + gid;
  int e1 = end[wid];
  // 4-deep unroll: 4 independent row-gathers in flight per group
  for (; e + 3 * G < e1; e += 4 * G) {
    int s0 = csr[e];
    int s1 = csr[e + G];
    int s2 = csr[e + 2 * G];
    int s3 = csr[e + 3 * G];
    bf16x8 v0 = *(const bf16x8*)(ts + (size_t)s0 * C + gl * 8);
    bf16x8 v1 = *(const bf16x8*)(ts + (size_t)s1 * C + gl * 8);
    bf16x8 v2 = *(const bf16x8*)(ts + (size_t)s2 * C + gl * 8);
    bf16x8 v3 = *(const bf16x8*)(ts + (size_t)s3 * C + gl * 8);
#pragma unroll
    for (int j = 0; j < 8; ++j)
      acc[j] += ((float)v0[j] + (float)v1[j]) + ((float)v2[j] + (float)v3[j]);
  }
  for (; e < e1; e += G) {
    int s0 = csr[e];
    bf16x8 v0 = *(const bf16x8*)(ts + (size_t)s0 * C + gl * 8);
#pragma unroll
    for (int j = 0; j < 8; ++j) acc[j] += (float)v0[j];
  }

  // cross-group reduce: fold groups down to lanes [0, LPG)
#pragma unroll
  for (int w = LPG; w < 64; w <<= 1) {
#pragma unroll
    for (int j = 0; j < 8; ++j) acc[j] += __shfl_xor(acc[j], w);
  }

  if (gid == 0) {
    float di = dis[wid];
    float o[8];
#pragma unroll
    for (int j = 0; j < 8; ++j) {
      o[j] = di * acc[j] + bias[gl * 8 + j];
      if (RELU) o[j] = fmaxf(o[j], 0.f);
    }
    if constexpr (sizeof(OutT) == 2) {
      bf16x8 pv;
#pragma unroll
      for (int j = 0; j < 8; ++j) pv[j] = (__bf16)o[j];
      *(bf16x8*)((__bf16*)out + (size_t)wid * C + gl * 8) = pv;
    } else {
      float4* op = (float4*)((float*)out + (size_t)wid * C + gl * 8);
      op[0] = make_float4(o[0], o[1], o[2], o[3]);
      op[1] = make_float4(o[4], o[5], o[6], o[7]);
    }
  }
}

extern "C" void kernel_launch(void* const* d_in, const int* in_sizes, int n_in,
                              void* d_out, int out_size, void* d_ws, size_t ws_size,
                              hipStream_t stream) {
  const float* x  = (const float*)d_in[0];
  const int*   ei = (const int*)d_in[1];
  const float* W1 = (const float*)d_in[2];
  const float* b1 = (const float*)d_in[3];
  const float* W2 = (const float*)d_in[4];
  const float* b2 = (const float*)d_in[5];
  float* out = (float*)d_out;

  const int N = in_sizes[0] / GCN_IN_C;  // 100000
  const int E = in_sizes[1] / 2;         // 1600000
  const int* src = ei;
  const int* dst = ei + E;
  const int NB = (N + BKT_NODES - 1) >> BKT_SHIFT;  // 391 buckets
  const int EB = (E + EPB - 1) / EPB;               // partition blocks

  // ws layout:
  //   dis[N] | t1s(bf16)[N*128] | a1(bf16)[N*128] | off[N] | end[N] | csr[E]
  //   | bcnt|bbase|bcur [512 each] | w1sp | w2sp
  //   part[E] aliases a1 (dead before agg1 writes a1)
  char* p = (char*)d_ws;
  float* dis = (float*)p;             p += (size_t)N * 4;
  __bf16* t1s = (__bf16*)p;           p += (size_t)N * GCN_HID * 2;
  __bf16* a1  = (__bf16*)p;           p += (size_t)N * GCN_HID * 2;
  int* off   = (int*)p;               p += (size_t)N * 4;
  int* end   = (int*)p;               p += (size_t)N * 4;
  int* csr   = (int*)p;               p += (size_t)E * 4;
  int* bcnt  = (int*)p;               p += 512 * 4;
  int* bbase = (int*)p;               p += 512 * 4;
  int* bcur  = (int*)p;               p += 512 * 4;
  __bf16* w1sp = (__bf16*)p;          p += (size_t)(GCN_IN_C / 32) * 2 * 4 * GCN_HID * 8 * 2;
  __bf16* w2sp = (__bf16*)p;
  unsigned int* part = (unsigned int*)a1;  // alias (6.4MB <= 25.6MB, dead before agg1)
  __bf16* t2s = t1s;  // layer-2 table reuses layer-1 table (row stride 64)

  // ---- weight pre-split (bf16 hi/lo, k-step-blocked)
  k_split_w<GCN_IN_C, GCN_HID>
      <<<((GCN_IN_C / 32) * 4 * GCN_HID + 255) / 256, 256, 0, stream>>>(W1, w1sp);
  k_split_w<GCN_HID, GCN_OUT>
      <<<((GCN_HID / 32) * 4 * GCN_OUT + 255) / 256, 256, 0, stream>>>(W2, w2sp);

  // ---- CSR build (bucketed counting sort)
  k_zero_i32<<<2, 256, 0, stream>>>(bcnt, 512);
  k_bucket_hist<<<EB, 256, 0, stream>>>(dst, bcnt, E, NB);
  k_scan_buckets<<<1, 512, 0, stream>>>(bcnt, bbase, bcur, NB);
  k_partition<<<EB, 256, 0, stream>>>(src, dst, bcur, part, E, NB);
  k_bucket_csr<<<NB, 256, 0, stream>>>(part, bbase, bcnt, off, end, dis, csr, N);

  // ---- layer 1: t1s = bf16(dis * x@W1); a1 = bf16(relu(dis*sum + b1))
  k_gemm_mfma<GCN_IN_C, GCN_HID>
      <<<(N + 63) / 64, 256, 0, stream>>>(x, w1sp, dis, t1s, N);
  k_agg_csr<GCN_HID, true, __bf16>
      <<<((size_t)N * 64 + 255) / 256, 256, 0, stream>>>(csr, off, end, t1s, dis, b1, a1, N);

  // ---- layer 2: t2s = bf16(dis * a1@W2); out = dis*sum + b2
  k_gemm_bf16A<GCN_HID, GCN_OUT>
      <<<(N + 63) / 64, 256, 0, stream>>>(a1, w2sp, dis, t2s, N);
  k_agg_csr<GCN_OUT, false, float>
      <<<((size_t)N * 64 + 255) / 256, 256, 0, stream>>>(csr, off, end, t2s, dis, b2, out, N);
}

// Round 12
// 218.845 us; speedup vs baseline: 1.1306x; 1.1046x over previous
//
#include <hip/hip_runtime.h>
#include <hip/hip_bf16.h>

// GCN encoder: out = GCNconv2( relu(GCNconv1(x)) )
// GCNconv(h,W,b) = D^-1/2 (A+I) D^-1/2 (h W) + b
//
// R11: group-per-node aggregation (no shfl fold, contiguous csr per group).
//   - agg: LPG=C/8 lanes own a full node row; 64/LPG consecutive nodes/wave;
//     4-deep edge unroll; epilogue writes whole row (bf16 or f32).
//   - split_w merged to one launch; zero via hipMemsetAsync.
//   GEMMs (split-bf16 swapped-operand barrier-free) unchanged from R10.

#define GCN_IN_C 256
#define GCN_HID  128
#define GCN_OUT  64

#define BKT_SHIFT 8
#define BKT_NODES 256
#define EPB 4096  // edges per block in partition kernels

typedef __bf16 bf16x8 __attribute__((ext_vector_type(8)));
typedef __bf16 bf16x4 __attribute__((ext_vector_type(4)));
typedef float f32x4 __attribute__((ext_vector_type(4)));

// P1a: bucket sizes
__global__ __launch_bounds__(256) void k_bucket_hist(const int* __restrict__ dst,
                                                     int* __restrict__ bcnt, int e, int nb) {
  __shared__ int h[512];
  int tid = threadIdx.x;
  h[tid] = 0; h[tid + 256] = 0;
  __syncthreads();
  int base = blockIdx.x * EPB;
#pragma unroll
  for (int j = 0; j < EPB / 256; ++j) {
    int i = base + j * 256 + tid;
    if (i < e) atomicAdd(&h[dst[i] >> BKT_SHIFT], 1);
  }
  __syncthreads();
  if (tid < nb && h[tid]) atomicAdd(&bcnt[tid], h[tid]);
  if (tid + 256 < nb && h[tid + 256]) atomicAdd(&bcnt[tid + 256], h[tid + 256]);
}

// exclusive scan of bucket sizes (nb <= 512), writes bbase and bcur
__global__ __launch_bounds__(512) void k_scan_buckets(const int* __restrict__ bcnt,
                                                      int* __restrict__ bbase,
                                                      int* __restrict__ bcur, int nb) {
  __shared__ int sh[512];
  int t = threadIdx.x;
  int v = (t < nb) ? bcnt[t] : 0;
  sh[t] = v;
  __syncthreads();
  for (int d = 1; d < 512; d <<= 1) {
    int x = (t >= d) ? sh[t - d] : 0;
    __syncthreads();
    sh[t] += x;
    __syncthreads();
  }
  if (t < nb) {
    int ex = sh[t] - v;
    bbase[t] = ex;
    bcur[t] = ex;
  }
}

// P1b: partition edges into bucket-contiguous regions (packed 4B)
__global__ __launch_bounds__(256) void k_partition(const int* __restrict__ src,
                                                   const int* __restrict__ dst,
                                                   int* __restrict__ bcur,
                                                   unsigned int* __restrict__ part,
                                                   int e, int nb) {
  __shared__ int h[512];
  __shared__ int base[512];
  int tid = threadIdx.x;
  h[tid] = 0; h[tid + 256] = 0;
  __syncthreads();
  int b0 = blockIdx.x * EPB;
  int s[EPB / 256], d[EPB / 256], rk[EPB / 256];
#pragma unroll
  for (int j = 0; j < EPB / 256; ++j) {
    int i = b0 + j * 256 + tid;
    if (i < e) {
      s[j] = src[i];
      d[j] = dst[i];
      rk[j] = atomicAdd(&h[d[j] >> BKT_SHIFT], 1);
    }
  }
  __syncthreads();
  if (tid < nb && h[tid]) base[tid] = atomicAdd(&bcur[tid], h[tid]);
  if (tid + 256 < nb && h[tid + 256]) base[tid + 256] = atomicAdd(&bcur[tid + 256], h[tid + 256]);
  __syncthreads();
#pragma unroll
  for (int j = 0; j < EPB / 256; ++j) {
    int i = b0 + j * 256 + tid;
    if (i < e) {
      int bk = d[j] >> BKT_SHIFT;
      unsigned int dl = (unsigned int)(d[j] & (BKT_NODES - 1));
      part[base[bk] + rk[j]] = (dl << 24) | (unsigned int)s[j];
    }
  }
}

// P2: per-bucket CSR finalize. One block per bucket.
__global__ __launch_bounds__(256) void k_bucket_csr(
    const unsigned int* __restrict__ part, const int* __restrict__ bbase,
    const int* __restrict__ bcnt, int* __restrict__ off, int* __restrict__ end,
    float* __restrict__ dis, int* __restrict__ csr, int n) {
  __shared__ int cnt[256];
  __shared__ int sc[256];
  __shared__ int cur[256];
  int b = blockIdx.x, tid = threadIdx.x;
  int node0 = b << BKT_SHIFT;
  int eb0 = bbase[b];
  int ebn = bcnt[b];
  cnt[tid] = 0;
  __syncthreads();
  for (int i = tid; i < ebn; i += 256) atomicAdd(&cnt[part[eb0 + i] >> 24], 1);
  __syncthreads();
  int v = cnt[tid];
  sc[tid] = v;
  __syncthreads();
  for (int dd = 1; dd < 256; dd <<= 1) {
    int x = (tid >= dd) ? sc[tid - dd] : 0;
    __syncthreads();
    sc[tid] += x;
    __syncthreads();
  }
  int lo = sc[tid] - v;  // exclusive
  cur[tid] = lo;
  int node = node0 + tid;
  if (node < n) {
    off[node] = eb0 + lo;
    end[node] = eb0 + lo + v;
    dis[node] = rsqrtf((float)v + 1.0f);
  }
  __syncthreads();
  for (int i = tid; i < ebn; i += 256) {
    unsigned int u = part[eb0 + i];
    int r = atomicAdd(&cur[u >> 24], 1);
    csr[eb0 + r] = (int)(u & 0xFFFFFFu);
  }
}

// Pre-split W1 and W2 (f32) into k-step-blocked bf16 hi/lo, one launch.
//   Wsp[ks][hl][g][n][8] ; k = ks*32 + g*8 + j
template<int K, int NOUT>
__device__ __forceinline__ void split_w_one(const float* __restrict__ W,
                                            __bf16* __restrict__ Wsp, int idx) {
  int n = idx % NOUT;
  int g = (idx / NOUT) & 3;
  int ks = idx / (4 * NOUT);
  __bf16* hi = Wsp + (size_t)ks * (2 * 4 * NOUT * 8) + ((size_t)g * NOUT + n) * 8;
  __bf16* lo = hi + 4 * NOUT * 8;
#pragma unroll
  for (int j = 0; j < 8; ++j) {
    float f = W[(size_t)(ks * 32 + g * 8 + j) * NOUT + n];
    __bf16 h = (__bf16)f;
    hi[j] = h;
    lo[j] = (__bf16)(f - (float)h);
  }
}

__global__ __launch_bounds__(256) void k_split_w_all(
    const float* __restrict__ W1, __bf16* __restrict__ w1sp,
    const float* __restrict__ W2, __bf16* __restrict__ w2sp) {
  constexpr int N1 = (GCN_IN_C / 32) * 4 * GCN_HID;  // 4096
  constexpr int N2 = (GCN_HID / 32) * 4 * GCN_OUT;   // 1024
  int idx = blockIdx.x * 256 + threadIdx.x;
  if (idx < N1) split_w_one<GCN_IN_C, GCN_HID>(W1, w1sp, idx);
  else if (idx < N1 + N2) split_w_one<GCN_HID, GCN_OUT>(W2, w2sp, idx - N1);
}

// Layer-1 GEMM: split-bf16 3-term, barrier-free, swapped operands.
// T[m] = bf16( dis[m] * (X[m] @ W) ). BM=64, 4 waves x 16 rows.
template<int K, int NOUT>
__global__ __launch_bounds__(256, 5) void k_gemm_mfma(
    const float* __restrict__ X, const __bf16* __restrict__ Wsp,
    const float* __restrict__ dis, __bf16* __restrict__ T, int M) {
  constexpr int BM = 64;
  constexpr int NF = NOUT / 16;
  constexpr int KSTEPS = K / 32;
  constexpr int TILE = 2 * 4 * NOUT * 8;

  const int tid = threadIdx.x;
  const int wave = tid >> 6;
  const int lane = tid & 63;
  const int l15 = lane & 15;
  const int lg = lane >> 4;
  const int r0w = blockIdx.x * BM + wave * 16;

  f32x4 acc[NF];
#pragma unroll
  for (int nf = 0; nf < NF; ++nf) acc[nf] = (f32x4){0.f, 0.f, 0.f, 0.f};

  int row = r0w + l15;
  int rowA = (row < M) ? row : (M - 1);

  auto loadA = [&](int ks, float4* v0, float4* v1) {
    const float* ap = X + (size_t)rowA * K + ks * 32 + lg * 8;
    *v0 = *(const float4*)ap;
    *v1 = *(const float4*)(ap + 4);
  };

  float4 ca0, ca1, na0, na1;
  loadA(0, &ca0, &ca1);

  const int boff = lg * NOUT * 8 + l15 * 8;
#pragma unroll 1
  for (int ks = 0; ks < KSTEPS; ++ks) {
    if (ks + 1 < KSTEPS) loadA(ks + 1, &na0, &na1);
    bf16x8 ah, al;
    {
      float va[8] = {ca0.x, ca0.y, ca0.z, ca0.w, ca1.x, ca1.y, ca1.z, ca1.w};
#pragma unroll
      for (int j = 0; j < 8; ++j) {
        __bf16 h = (__bf16)va[j];
        ah[j] = h;
        al[j] = (__bf16)(va[j] - (float)h);
      }
    }
    const __bf16* wk = Wsp + (size_t)ks * TILE;
    const __bf16* wkl = wk + 4 * NOUT * 8;
#pragma unroll
    for (int nf = 0; nf < NF; ++nf) {
      bf16x8 bh = *(const bf16x8*)(wk + boff + nf * 128);
      bf16x8 bl = *(const bf16x8*)(wkl + boff + nf * 128);
      acc[nf] = __builtin_amdgcn_mfma_f32_16x16x32_bf16(bh, ah, acc[nf], 0, 0, 0);
      acc[nf] = __builtin_amdgcn_mfma_f32_16x16x32_bf16(bl, ah, acc[nf], 0, 0, 0);
      acc[nf] = __builtin_amdgcn_mfma_f32_16x16x32_bf16(bh, al, acc[nf], 0, 0, 0);
    }
    ca0 = na0;
    ca1 = na1;
  }

  if (row < M) {
    float dv = dis[row];
#pragma unroll
    for (int nf = 0; nf < NF; ++nf) {
      bf16x4 pk;
#pragma unroll
      for (int r = 0; r < 4; ++r) pk[r] = (__bf16)(dv * acc[nf][r]);
      *(bf16x4*)(T + (size_t)row * NOUT + nf * 16 + lg * 4) = pk;
    }
  }
}

// Layer-2 GEMM: A already bf16 (exact), 2-term MFMA, barrier-free, swapped.
template<int K, int NOUT>
__global__ __launch_bounds__(256) void k_gemm_bf16A(
    const __bf16* __restrict__ A, const __bf16* __restrict__ Wsp,
    const float* __restrict__ dis, __bf16* __restrict__ T, int M) {
  constexpr int BM = 64;
  constexpr int NF = NOUT / 16;
  constexpr int KSTEPS = K / 32;
  constexpr int TILE = 2 * 4 * NOUT * 8;

  const int tid = threadIdx.x;
  const int wave = tid >> 6;
  const int lane = tid & 63;
  const int l15 = lane & 15;
  const int lg = lane >> 4;
  const int r0w = blockIdx.x * BM + wave * 16;

  f32x4 acc[NF];
#pragma unroll
  for (int nf = 0; nf < NF; ++nf) acc[nf] = (f32x4){0.f, 0.f, 0.f, 0.f};

  int row = r0w + l15;
  int rowA = (row < M) ? row : (M - 1);

  bf16x8 ca, na;
  ca = *(const bf16x8*)(A + (size_t)rowA * K + lg * 8);

  const int boff = lg * NOUT * 8 + l15 * 8;
#pragma unroll 1
  for (int ks = 0; ks < KSTEPS; ++ks) {
    if (ks + 1 < KSTEPS)
      na = *(const bf16x8*)(A + (size_t)rowA * K + (ks + 1) * 32 + lg * 8);
    const __bf16* wk = Wsp + (size_t)ks * TILE;
    const __bf16* wkl = wk + 4 * NOUT * 8;
#pragma unroll
    for (int nf = 0; nf < NF; ++nf) {
      bf16x8 bh = *(const bf16x8*)(wk + boff + nf * 128);
      bf16x8 bl = *(const bf16x8*)(wkl + boff + nf * 128);
      acc[nf] = __builtin_amdgcn_mfma_f32_16x16x32_bf16(bh, ca, acc[nf], 0, 0, 0);
      acc[nf] = __builtin_amdgcn_mfma_f32_16x16x32_bf16(bl, ca, acc[nf], 0, 0, 0);
    }
    ca = na;
  }

  if (row < M) {
    float dv = dis[row];
#pragma unroll
    for (int nf = 0; nf < NF; ++nf) {
      bf16x4 pk;
#pragma unroll
      for (int r = 0; r < 4; ++r) pk[r] = (__bf16)(dv * acc[nf][r]);
      *(bf16x4*)(T + (size_t)row * NOUT + nf * 16 + lg * 4) = pk;
    }
  }
}

// R11 CSR gather aggregation: one LPG-lane group per node (full row per group).
// No cross-group fold; group's csr segment is contiguous; 4-deep unroll.
// o = dis[i]*sum + bias; if RELU o=max(o,0); store OutT (bf16 or f32 row).
template<int C, bool RELU, typename OutT>
__global__ __launch_bounds__(256) void k_agg_csr(
    const int* __restrict__ csr, const int* __restrict__ off,
    const int* __restrict__ end, const __bf16* __restrict__ ts,
    const float* __restrict__ dis, const float* __restrict__ bias,
    OutT* __restrict__ out, int n) {
  constexpr int LPG = C / 8;   // lanes per group: 16 (C=128), 8 (C=64)
  int gtid = blockIdx.x * 256 + threadIdx.x;
  int node = gtid / LPG;       // consecutive nodes across the wave
  int gl = gtid % LPG;
  if (node >= n) return;

  float acc[8];
  {  // self term
    bf16x8 v = *(const bf16x8*)(ts + (size_t)node * C + gl * 8);
#pragma unroll
    for (int j = 0; j < 8; ++j) acc[j] = (float)v[j];
  }

  int e = off[node];
  int e1 = end[node];
  // 4-deep unroll: 4 independent row-gathers in flight per group
  for (; e + 4 <= e1; e += 4) {
    int s0 = csr[e];
    int s1 = csr[e + 1];
    int s2 = csr[e + 2];
    int s3 = csr[e + 3];
    bf16x8 v0 = *(const bf16x8*)(ts + (size_t)s0 * C + gl * 8);
    bf16x8 v1 = *(const bf16x8*)(ts + (size_t)s1 * C + gl * 8);
    bf16x8 v2 = *(const bf16x8*)(ts + (size_t)s2 * C + gl * 8);
    bf16x8 v3 = *(const bf16x8*)(ts + (size_t)s3 * C + gl * 8);
#pragma unroll
    for (int j = 0; j < 8; ++j)
      acc[j] += ((float)v0[j] + (float)v1[j]) + ((float)v2[j] + (float)v3[j]);
  }
  for (; e < e1; ++e) {
    int s0 = csr[e];
    bf16x8 v0 = *(const bf16x8*)(ts + (size_t)s0 * C + gl * 8);
#pragma unroll
    for (int j = 0; j < 8; ++j) acc[j] += (float)v0[j];
  }

  float di = dis[node];
  float o[8];
#pragma unroll
  for (int j = 0; j < 8; ++j) {
    o[j] = di * acc[j] + bias[gl * 8 + j];
    if (RELU) o[j] = fmaxf(o[j], 0.f);
  }
  if constexpr (sizeof(OutT) == 2) {
    bf16x8 pv;
#pragma unroll
    for (int j = 0; j < 8; ++j) pv[j] = (__bf16)o[j];
    *(bf16x8*)((__bf16*)out + (size_t)node * C + gl * 8) = pv;
  } else {
    float4* op = (float4*)((float*)out + (size_t)node * C + gl * 8);
    op[0] = make_float4(o[0], o[1], o[2], o[3]);
    op[1] = make_float4(o[4], o[5], o[6], o[7]);
  }
}

extern "C" void kernel_launch(void* const* d_in, const int* in_sizes, int n_in,
                              void* d_out, int out_size, void* d_ws, size_t ws_size,
                              hipStream_t stream) {
  const float* x  = (const float*)d_in[0];
  const int*   ei = (const int*)d_in[1];
  const float* W1 = (const float*)d_in[2];
  const float* b1 = (const float*)d_in[3];
  const float* W2 = (const float*)d_in[4];
  const float* b2 = (const float*)d_in[5];
  float* out = (float*)d_out;

  const int N = in_sizes[0] / GCN_IN_C;  // 100000
  const int E = in_sizes[1] / 2;         // 1600000
  const int* src = ei;
  const int* dst = ei + E;
  const int NB = (N + BKT_NODES - 1) >> BKT_SHIFT;  // 391 buckets
  const int EB = (E + EPB - 1) / EPB;               // partition blocks

  // ws layout:
  //   dis[N] | t1s(bf16)[N*128] | a1(bf16)[N*128] | off[N] | end[N] | csr[E]
  //   | bcnt|bbase|bcur [512 each] | w1sp | w2sp
  //   part[E] aliases a1 (dead before agg1 writes a1)
  char* p = (char*)d_ws;
  float* dis = (float*)p;             p += (size_t)N * 4;
  __bf16* t1s = (__bf16*)p;           p += (size_t)N * GCN_HID * 2;
  __bf16* a1  = (__bf16*)p;           p += (size_t)N * GCN_HID * 2;
  int* off   = (int*)p;               p += (size_t)N * 4;
  int* end   = (int*)p;               p += (size_t)N * 4;
  int* csr   = (int*)p;               p += (size_t)E * 4;
  int* bcnt  = (int*)p;               p += 512 * 4;
  int* bbase = (int*)p;               p += 512 * 4;
  int* bcur  = (int*)p;               p += 512 * 4;
  __bf16* w1sp = (__bf16*)p;          p += (size_t)(GCN_IN_C / 32) * 2 * 4 * GCN_HID * 8 * 2;
  __bf16* w2sp = (__bf16*)p;
  unsigned int* part = (unsigned int*)a1;  // alias (6.4MB <= 25.6MB, dead before agg1)
  __bf16* t2s = t1s;  // layer-2 table reuses layer-1 table (row stride 64)

  // ---- weight pre-split (one launch) + zero via memset
  k_split_w_all<<<(4096 + 1024 + 255) / 256, 256, 0, stream>>>(W1, w1sp, W2, w2sp);
  hipMemsetAsync(bcnt, 0, 512 * sizeof(int), stream);

  // ---- CSR build (bucketed counting sort)
  k_bucket_hist<<<EB, 256, 0, stream>>>(dst, bcnt, E, NB);
  k_scan_buckets<<<1, 512, 0, stream>>>(bcnt, bbase, bcur, NB);
  k_partition<<<EB, 256, 0, stream>>>(src, dst, bcur, part, E, NB);
  k_bucket_csr<<<NB, 256, 0, stream>>>(part, bbase, bcnt, off, end, dis, csr, N);

  // ---- layer 1: t1s = bf16(dis * x@W1); a1 = bf16(relu(dis*sum + b1))
  k_gemm_mfma<GCN_IN_C, GCN_HID>
      <<<(N + 63) / 64, 256, 0, stream>>>(x, w1sp, dis, t1s, N);
  k_agg_csr<GCN_HID, true, __bf16>
      <<<((size_t)N * (GCN_HID / 8) + 255) / 256, 256, 0, stream>>>(csr, off, end, t1s, dis, b1, a1, N);

  // ---- layer 2: t2s = bf16(dis * a1@W2); out = dis*sum + b2
  k_gemm_bf16A<GCN_HID, GCN_OUT>
      <<<(N + 63) / 64, 256, 0, stream>>>(a1, w2sp, dis, t2s, N);
  k_agg_csr<GCN_OUT, false, float>
      <<<((size_t)N * (GCN_OUT / 8) + 255) / 256, 256, 0, stream>>>(csr, off, end, t2s, dis, b2, out, N);
}

// Round 13
// 215.844 us; speedup vs baseline: 1.1463x; 1.0139x over previous
//
#include <hip/hip_runtime.h>
#include <hip/hip_bf16.h>

// GCN encoder: out = GCNconv2( relu(GCNconv1(x)) )
// GCNconv(h,W,b) = D^-1/2 (A+I) D^-1/2 (h W) + b
//
// R12: B-register-reuse GEMM. Each wave computes 4 row-tiles (64 rows);
//   B fragments loaded once per (ks,nf) serve 4 tiles -> L2 W-traffic /4.
//   Barrier-free, no LDS. agg (group-per-node) + CSR build from R11.

#define GCN_IN_C 256
#define GCN_HID  128
#define GCN_OUT  64

#define BKT_SHIFT 8
#define BKT_NODES 256
#define EPB 4096  // edges per block in partition kernels

typedef __bf16 bf16x8 __attribute__((ext_vector_type(8)));
typedef __bf16 bf16x4 __attribute__((ext_vector_type(4)));
typedef float f32x4 __attribute__((ext_vector_type(4)));

// P1a: bucket sizes
__global__ __launch_bounds__(256) void k_bucket_hist(const int* __restrict__ dst,
                                                     int* __restrict__ bcnt, int e, int nb) {
  __shared__ int h[512];
  int tid = threadIdx.x;
  h[tid] = 0; h[tid + 256] = 0;
  __syncthreads();
  int base = blockIdx.x * EPB;
#pragma unroll
  for (int j = 0; j < EPB / 256; ++j) {
    int i = base + j * 256 + tid;
    if (i < e) atomicAdd(&h[dst[i] >> BKT_SHIFT], 1);
  }
  __syncthreads();
  if (tid < nb && h[tid]) atomicAdd(&bcnt[tid], h[tid]);
  if (tid + 256 < nb && h[tid + 256]) atomicAdd(&bcnt[tid + 256], h[tid + 256]);
}

// exclusive scan of bucket sizes (nb <= 512), writes bbase and bcur
__global__ __launch_bounds__(512) void k_scan_buckets(const int* __restrict__ bcnt,
                                                      int* __restrict__ bbase,
                                                      int* __restrict__ bcur, int nb) {
  __shared__ int sh[512];
  int t = threadIdx.x;
  int v = (t < nb) ? bcnt[t] : 0;
  sh[t] = v;
  __syncthreads();
  for (int d = 1; d < 512; d <<= 1) {
    int x = (t >= d) ? sh[t - d] : 0;
    __syncthreads();
    sh[t] += x;
    __syncthreads();
  }
  if (t < nb) {
    int ex = sh[t] - v;
    bbase[t] = ex;
    bcur[t] = ex;
  }
}

// P1b: partition edges into bucket-contiguous regions (packed 4B)
__global__ __launch_bounds__(256) void k_partition(const int* __restrict__ src,
                                                   const int* __restrict__ dst,
                                                   int* __restrict__ bcur,
                                                   unsigned int* __restrict__ part,
                                                   int e, int nb) {
  __shared__ int h[512];
  __shared__ int base[512];
  int tid = threadIdx.x;
  h[tid] = 0; h[tid + 256] = 0;
  __syncthreads();
  int b0 = blockIdx.x * EPB;
  int s[EPB / 256], d[EPB / 256], rk[EPB / 256];
#pragma unroll
  for (int j = 0; j < EPB / 256; ++j) {
    int i = b0 + j * 256 + tid;
    if (i < e) {
      s[j] = src[i];
      d[j] = dst[i];
      rk[j] = atomicAdd(&h[d[j] >> BKT_SHIFT], 1);
    }
  }
  __syncthreads();
  if (tid < nb && h[tid]) base[tid] = atomicAdd(&bcur[tid], h[tid]);
  if (tid + 256 < nb && h[tid + 256]) base[tid + 256] = atomicAdd(&bcur[tid + 256], h[tid + 256]);
  __syncthreads();
#pragma unroll
  for (int j = 0; j < EPB / 256; ++j) {
    int i = b0 + j * 256 + tid;
    if (i < e) {
      int bk = d[j] >> BKT_SHIFT;
      unsigned int dl = (unsigned int)(d[j] & (BKT_NODES - 1));
      part[base[bk] + rk[j]] = (dl << 24) | (unsigned int)s[j];
    }
  }
}

// P2: per-bucket CSR finalize. One block per bucket.
__global__ __launch_bounds__(256) void k_bucket_csr(
    const unsigned int* __restrict__ part, const int* __restrict__ bbase,
    const int* __restrict__ bcnt, int* __restrict__ off, int* __restrict__ end,
    float* __restrict__ dis, int* __restrict__ csr, int n) {
  __shared__ int cnt[256];
  __shared__ int sc[256];
  __shared__ int cur[256];
  int b = blockIdx.x, tid = threadIdx.x;
  int node0 = b << BKT_SHIFT;
  int eb0 = bbase[b];
  int ebn = bcnt[b];
  cnt[tid] = 0;
  __syncthreads();
  for (int i = tid; i < ebn; i += 256) atomicAdd(&cnt[part[eb0 + i] >> 24], 1);
  __syncthreads();
  int v = cnt[tid];
  sc[tid] = v;
  __syncthreads();
  for (int dd = 1; dd < 256; dd <<= 1) {
    int x = (tid >= dd) ? sc[tid - dd] : 0;
    __syncthreads();
    sc[tid] += x;
    __syncthreads();
  }
  int lo = sc[tid] - v;  // exclusive
  cur[tid] = lo;
  int node = node0 + tid;
  if (node < n) {
    off[node] = eb0 + lo;
    end[node] = eb0 + lo + v;
    dis[node] = rsqrtf((float)v + 1.0f);
  }
  __syncthreads();
  for (int i = tid; i < ebn; i += 256) {
    unsigned int u = part[eb0 + i];
    int r = atomicAdd(&cur[u >> 24], 1);
    csr[eb0 + r] = (int)(u & 0xFFFFFFu);
  }
}

// Pre-split W1 and W2 (f32) into k-step-blocked bf16 hi/lo, one launch.
//   Wsp[ks][hl][g][n][8] ; k = ks*32 + g*8 + j
template<int K, int NOUT>
__device__ __forceinline__ void split_w_one(const float* __restrict__ W,
                                            __bf16* __restrict__ Wsp, int idx) {
  int n = idx % NOUT;
  int g = (idx / NOUT) & 3;
  int ks = idx / (4 * NOUT);
  __bf16* hi = Wsp + (size_t)ks * (2 * 4 * NOUT * 8) + ((size_t)g * NOUT + n) * 8;
  __bf16* lo = hi + 4 * NOUT * 8;
#pragma unroll
  for (int j = 0; j < 8; ++j) {
    float f = W[(size_t)(ks * 32 + g * 8 + j) * NOUT + n];
    __bf16 h = (__bf16)f;
    hi[j] = h;
    lo[j] = (__bf16)(f - (float)h);
  }
}

__global__ __launch_bounds__(256) void k_split_w_all(
    const float* __restrict__ W1, __bf16* __restrict__ w1sp,
    const float* __restrict__ W2, __bf16* __restrict__ w2sp) {
  constexpr int N1 = (GCN_IN_C / 32) * 4 * GCN_HID;  // 4096
  constexpr int N2 = (GCN_HID / 32) * 4 * GCN_OUT;   // 1024
  int idx = blockIdx.x * 256 + threadIdx.x;
  if (idx < N1) split_w_one<GCN_IN_C, GCN_HID>(W1, w1sp, idx);
  else if (idx < N1 + N2) split_w_one<GCN_HID, GCN_OUT>(W2, w2sp, idx - N1);
}

// Layer-1 GEMM: split-bf16 3-term, barrier-free, swapped operands,
// 4 row-tiles (64 rows) per wave, B-frag registers reused across tiles.
// T[m] = bf16( dis[m] * (X[m] @ W) ).
template<int K, int NOUT>
__global__ __launch_bounds__(256, 2) void k_gemm_mfma(
    const float* __restrict__ X, const __bf16* __restrict__ Wsp,
    const float* __restrict__ dis, __bf16* __restrict__ T, int M) {
  constexpr int NF = NOUT / 16;
  constexpr int KSTEPS = K / 32;
  constexpr int TILE = 2 * 4 * NOUT * 8;

  const int tid = threadIdx.x;
  const int wave = tid >> 6;
  const int lane = tid & 63;
  const int l15 = lane & 15;
  const int lg = lane >> 4;
  const int base = (blockIdx.x * 4 + wave) * 64;  // 64 rows per wave

  f32x4 acc[4][NF];
#pragma unroll
  for (int t = 0; t < 4; ++t)
#pragma unroll
    for (int nf = 0; nf < NF; ++nf) acc[t][nf] = (f32x4){0.f, 0.f, 0.f, 0.f};

  int rowA[4];
#pragma unroll
  for (int t = 0; t < 4; ++t) {
    int r = base + t * 16 + l15;
    rowA[t] = (r < M) ? r : (M - 1);  // clamp: OOB rows never stored
  }

  const int boff = lg * NOUT * 8 + l15 * 8;
#pragma unroll 1
  for (int ks = 0; ks < KSTEPS; ++ks) {
    const int k0 = ks * 32 + lg * 8;
    // ---- A for all 4 tiles: load f32, split hi/lo in regs
    bf16x8 ah[4], al[4];
#pragma unroll
    for (int t = 0; t < 4; ++t) {
      const float* ap = X + (size_t)rowA[t] * K + k0;
      float4 v0 = *(const float4*)ap;
      float4 v1 = *(const float4*)(ap + 4);
      float va[8] = {v0.x, v0.y, v0.z, v0.w, v1.x, v1.y, v1.z, v1.w};
#pragma unroll
      for (int j = 0; j < 8; ++j) {
        __bf16 h = (__bf16)va[j];
        ah[t][j] = h;
        al[t][j] = (__bf16)(va[j] - (float)h);
      }
    }
    // ---- B per (ks,nf) from L2, reused by 4 tiles; swapped operands
    const __bf16* wk = Wsp + (size_t)ks * TILE;
    const __bf16* wkl = wk + 4 * NOUT * 8;
#pragma unroll
    for (int nf = 0; nf < NF; ++nf) {
      bf16x8 bh = *(const bf16x8*)(wk + boff + nf * 128);
      bf16x8 bl = *(const bf16x8*)(wkl + boff + nf * 128);
#pragma unroll
      for (int t = 0; t < 4; ++t) {
        acc[t][nf] = __builtin_amdgcn_mfma_f32_16x16x32_bf16(bh, ah[t], acc[t][nf], 0, 0, 0);
        acc[t][nf] = __builtin_amdgcn_mfma_f32_16x16x32_bf16(bl, ah[t], acc[t][nf], 0, 0, 0);
        acc[t][nf] = __builtin_amdgcn_mfma_f32_16x16x32_bf16(bh, al[t], acc[t][nf], 0, 0, 0);
      }
    }
  }

  // ---- epilogue: lane holds T[row][nf*16 + lg*4 + r] -> packed 8B stores
#pragma unroll
  for (int t = 0; t < 4; ++t) {
    int row = base + t * 16 + l15;
    if (row < M) {
      float dv = dis[row];
#pragma unroll
      for (int nf = 0; nf < NF; ++nf) {
        bf16x4 pk;
#pragma unroll
        for (int r = 0; r < 4; ++r) pk[r] = (__bf16)(dv * acc[t][nf][r]);
        *(bf16x4*)(T + (size_t)row * NOUT + nf * 16 + lg * 4) = pk;
      }
    }
  }
}

// Layer-2 GEMM: A exact bf16, 2-term, barrier-free, swapped, 4 tiles/wave.
template<int K, int NOUT>
__global__ __launch_bounds__(256, 4) void k_gemm_bf16A(
    const __bf16* __restrict__ A, const __bf16* __restrict__ Wsp,
    const float* __restrict__ dis, __bf16* __restrict__ T, int M) {
  constexpr int NF = NOUT / 16;
  constexpr int KSTEPS = K / 32;
  constexpr int TILE = 2 * 4 * NOUT * 8;

  const int tid = threadIdx.x;
  const int wave = tid >> 6;
  const int lane = tid & 63;
  const int l15 = lane & 15;
  const int lg = lane >> 4;
  const int base = (blockIdx.x * 4 + wave) * 64;

  f32x4 acc[4][NF];
#pragma unroll
  for (int t = 0; t < 4; ++t)
#pragma unroll
    for (int nf = 0; nf < NF; ++nf) acc[t][nf] = (f32x4){0.f, 0.f, 0.f, 0.f};

  int rowA[4];
#pragma unroll
  for (int t = 0; t < 4; ++t) {
    int r = base + t * 16 + l15;
    rowA[t] = (r < M) ? r : (M - 1);
  }

  const int boff = lg * NOUT * 8 + l15 * 8;
#pragma unroll 1
  for (int ks = 0; ks < KSTEPS; ++ks) {
    const int k0 = ks * 32 + lg * 8;
    bf16x8 ca[4];
#pragma unroll
    for (int t = 0; t < 4; ++t)
      ca[t] = *(const bf16x8*)(A + (size_t)rowA[t] * K + k0);
    const __bf16* wk = Wsp + (size_t)ks * TILE;
    const __bf16* wkl = wk + 4 * NOUT * 8;
#pragma unroll
    for (int nf = 0; nf < NF; ++nf) {
      bf16x8 bh = *(const bf16x8*)(wk + boff + nf * 128);
      bf16x8 bl = *(const bf16x8*)(wkl + boff + nf * 128);
#pragma unroll
      for (int t = 0; t < 4; ++t) {
        acc[t][nf] = __builtin_amdgcn_mfma_f32_16x16x32_bf16(bh, ca[t], acc[t][nf], 0, 0, 0);
        acc[t][nf] = __builtin_amdgcn_mfma_f32_16x16x32_bf16(bl, ca[t], acc[t][nf], 0, 0, 0);
      }
    }
  }

#pragma unroll
  for (int t = 0; t < 4; ++t) {
    int row = base + t * 16 + l15;
    if (row < M) {
      float dv = dis[row];
#pragma unroll
      for (int nf = 0; nf < NF; ++nf) {
        bf16x4 pk;
#pragma unroll
        for (int r = 0; r < 4; ++r) pk[r] = (__bf16)(dv * acc[t][nf][r]);
        *(bf16x4*)(T + (size_t)row * NOUT + nf * 16 + lg * 4) = pk;
      }
    }
  }
}

// CSR gather aggregation: one LPG-lane group per node (full row per group).
// No cross-group fold; group's csr segment is contiguous; 4-deep unroll.
// o = dis[i]*sum + bias; if RELU o=max(o,0); store OutT (bf16 or f32 row).
template<int C, bool RELU, typename OutT>
__global__ __launch_bounds__(256) void k_agg_csr(
    const int* __restrict__ csr, const int* __restrict__ off,
    const int* __restrict__ end, const __bf16* __restrict__ ts,
    const float* __restrict__ dis, const float* __restrict__ bias,
    OutT* __restrict__ out, int n) {
  constexpr int LPG = C / 8;   // lanes per group: 16 (C=128), 8 (C=64)
  int gtid = blockIdx.x * 256 + threadIdx.x;
  int node = gtid / LPG;       // consecutive nodes across the wave
  int gl = gtid % LPG;
  if (node >= n) return;

  float acc[8];
  {  // self term
    bf16x8 v = *(const bf16x8*)(ts + (size_t)node * C + gl * 8);
#pragma unroll
    for (int j = 0; j < 8; ++j) acc[j] = (float)v[j];
  }

  int e = off[node];
  int e1 = end[node];
  for (; e + 4 <= e1; e += 4) {
    int s0 = csr[e];
    int s1 = csr[e + 1];
    int s2 = csr[e + 2];
    int s3 = csr[e + 3];
    bf16x8 v0 = *(const bf16x8*)(ts + (size_t)s0 * C + gl * 8);
    bf16x8 v1 = *(const bf16x8*)(ts + (size_t)s1 * C + gl * 8);
    bf16x8 v2 = *(const bf16x8*)(ts + (size_t)s2 * C + gl * 8);
    bf16x8 v3 = *(const bf16x8*)(ts + (size_t)s3 * C + gl * 8);
#pragma unroll
    for (int j = 0; j < 8; ++j)
      acc[j] += ((float)v0[j] + (float)v1[j]) + ((float)v2[j] + (float)v3[j]);
  }
  for (; e < e1; ++e) {
    int s0 = csr[e];
    bf16x8 v0 = *(const bf16x8*)(ts + (size_t)s0 * C + gl * 8);
#pragma unroll
    for (int j = 0; j < 8; ++j) acc[j] += (float)v0[j];
  }

  float di = dis[node];
  float o[8];
#pragma unroll
  for (int j = 0; j < 8; ++j) {
    o[j] = di * acc[j] + bias[gl * 8 + j];
    if (RELU) o[j] = fmaxf(o[j], 0.f);
  }
  if constexpr (sizeof(OutT) == 2) {
    bf16x8 pv;
#pragma unroll
    for (int j = 0; j < 8; ++j) pv[j] = (__bf16)o[j];
    *(bf16x8*)((__bf16*)out + (size_t)node * C + gl * 8) = pv;
  } else {
    float4* op = (float4*)((float*)out + (size_t)node * C + gl * 8);
    op[0] = make_float4(o[0], o[1], o[2], o[3]);
    op[1] = make_float4(o[4], o[5], o[6], o[7]);
  }
}

extern "C" void kernel_launch(void* const* d_in, const int* in_sizes, int n_in,
                              void* d_out, int out_size, void* d_ws, size_t ws_size,
                              hipStream_t stream) {
  const float* x  = (const float*)d_in[0];
  const int*   ei = (const int*)d_in[1];
  const float* W1 = (const float*)d_in[2];
  const float* b1 = (const float*)d_in[3];
  const float* W2 = (const float*)d_in[4];
  const float* b2 = (const float*)d_in[5];
  float* out = (float*)d_out;

  const int N = in_sizes[0] / GCN_IN_C;  // 100000
  const int E = in_sizes[1] / 2;         // 1600000
  const int* src = ei;
  const int* dst = ei + E;
  const int NB = (N + BKT_NODES - 1) >> BKT_SHIFT;  // 391 buckets
  const int EB = (E + EPB - 1) / EPB;               // partition blocks

  // ws layout:
  //   dis[N] | t1s(bf16)[N*128] | a1(bf16)[N*128] | off[N] | end[N] | csr[E]
  //   | bcnt|bbase|bcur [512 each] | w1sp | w2sp
  //   part[E] aliases a1 (dead before agg1 writes a1)
  char* p = (char*)d_ws;
  float* dis = (float*)p;             p += (size_t)N * 4;
  __bf16* t1s = (__bf16*)p;           p += (size_t)N * GCN_HID * 2;
  __bf16* a1  = (__bf16*)p;           p += (size_t)N * GCN_HID * 2;
  int* off   = (int*)p;               p += (size_t)N * 4;
  int* end   = (int*)p;               p += (size_t)N * 4;
  int* csr   = (int*)p;               p += (size_t)E * 4;
  int* bcnt  = (int*)p;               p += 512 * 4;
  int* bbase = (int*)p;               p += 512 * 4;
  int* bcur  = (int*)p;               p += 512 * 4;
  __bf16* w1sp = (__bf16*)p;          p += (size_t)(GCN_IN_C / 32) * 2 * 4 * GCN_HID * 8 * 2;
  __bf16* w2sp = (__bf16*)p;
  unsigned int* part = (unsigned int*)a1;  // alias (6.4MB <= 25.6MB, dead before agg1)
  __bf16* t2s = t1s;  // layer-2 table reuses layer-1 table (row stride 64)

  // ---- weight pre-split (one launch) + zero via memset
  k_split_w_all<<<(4096 + 1024 + 255) / 256, 256, 0, stream>>>(W1, w1sp, W2, w2sp);
  hipMemsetAsync(bcnt, 0, 512 * sizeof(int), stream);

  // ---- CSR build (bucketed counting sort)
  k_bucket_hist<<<EB, 256, 0, stream>>>(dst, bcnt, E, NB);
  k_scan_buckets<<<1, 512, 0, stream>>>(bcnt, bbase, bcur, NB);
  k_partition<<<EB, 256, 0, stream>>>(src, dst, bcur, part, E, NB);
  k_bucket_csr<<<NB, 256, 0, stream>>>(part, bbase, bcnt, off, end, dis, csr, N);

  // ---- layer 1: t1s = bf16(dis * x@W1); a1 = bf16(relu(dis*sum + b1))
  k_gemm_mfma<GCN_IN_C, GCN_HID>
      <<<(N + 255) / 256, 256, 0, stream>>>(x, w1sp, dis, t1s, N);
  k_agg_csr<GCN_HID, true, __bf16>
      <<<((size_t)N * (GCN_HID / 8) + 255) / 256, 256, 0, stream>>>(csr, off, end, t1s, dis, b1, a1, N);

  // ---- layer 2: t2s = bf16(dis * a1@W2); out = dis*sum + b2
  k_gemm_bf16A<GCN_HID, GCN_OUT>
      <<<(N + 255) / 256, 256, 0, stream>>>(a1, w2sp, dis, t2s, N);
  k_agg_csr<GCN_OUT, false, float>
      <<<((size_t)N * (GCN_OUT / 8) + 255) / 256, 256, 0, stream>>>(csr, off, end, t2s, dis, b2, out, N);
}

// Round 14
// 205.167 us; speedup vs baseline: 1.2060x; 1.0520x over previous
//
#include <hip/hip_runtime.h>
#include <hip/hip_bf16.h>

// GCN encoder: out = GCNconv2( relu(GCNconv1(x)) )
// GCNconv(h,W,b) = D^-1/2 (A+I) D^-1/2 (h W) + b
//
// R13: LDS-resident B, barrier-free k-loop.
//   gemm1: W1-hi (64KB) staged to LDS once (global_load_lds + 1 barrier);
//          W1-lo + A register-prefetched 1 kstep ahead; 3-term split bf16.
//   gemm2: whole W2sp (32KB) in LDS; A bf16 prefetched; 2-term.
//   agg (group-per-node) + CSR build unchanged from R11.

#define GCN_IN_C 256
#define GCN_HID  128
#define GCN_OUT  64

#define BKT_SHIFT 8
#define BKT_NODES 256
#define EPB 4096  // edges per block in partition kernels

typedef __bf16 bf16x8 __attribute__((ext_vector_type(8)));
typedef __bf16 bf16x4 __attribute__((ext_vector_type(4)));
typedef float f32x4 __attribute__((ext_vector_type(4)));

// P1a: bucket sizes
__global__ __launch_bounds__(256) void k_bucket_hist(const int* __restrict__ dst,
                                                     int* __restrict__ bcnt, int e, int nb) {
  __shared__ int h[512];
  int tid = threadIdx.x;
  h[tid] = 0; h[tid + 256] = 0;
  __syncthreads();
  int base = blockIdx.x * EPB;
#pragma unroll
  for (int j = 0; j < EPB / 256; ++j) {
    int i = base + j * 256 + tid;
    if (i < e) atomicAdd(&h[dst[i] >> BKT_SHIFT], 1);
  }
  __syncthreads();
  if (tid < nb && h[tid]) atomicAdd(&bcnt[tid], h[tid]);
  if (tid + 256 < nb && h[tid + 256]) atomicAdd(&bcnt[tid + 256], h[tid + 256]);
}

// exclusive scan of bucket sizes (nb <= 512), writes bbase and bcur
__global__ __launch_bounds__(512) void k_scan_buckets(const int* __restrict__ bcnt,
                                                      int* __restrict__ bbase,
                                                      int* __restrict__ bcur, int nb) {
  __shared__ int sh[512];
  int t = threadIdx.x;
  int v = (t < nb) ? bcnt[t] : 0;
  sh[t] = v;
  __syncthreads();
  for (int d = 1; d < 512; d <<= 1) {
    int x = (t >= d) ? sh[t - d] : 0;
    __syncthreads();
    sh[t] += x;
    __syncthreads();
  }
  if (t < nb) {
    int ex = sh[t] - v;
    bbase[t] = ex;
    bcur[t] = ex;
  }
}

// P1b: partition edges into bucket-contiguous regions (packed 4B)
__global__ __launch_bounds__(256) void k_partition(const int* __restrict__ src,
                                                   const int* __restrict__ dst,
                                                   int* __restrict__ bcur,
                                                   unsigned int* __restrict__ part,
                                                   int e, int nb) {
  __shared__ int h[512];
  __shared__ int base[512];
  int tid = threadIdx.x;
  h[tid] = 0; h[tid + 256] = 0;
  __syncthreads();
  int b0 = blockIdx.x * EPB;
  int s[EPB / 256], d[EPB / 256], rk[EPB / 256];
#pragma unroll
  for (int j = 0; j < EPB / 256; ++j) {
    int i = b0 + j * 256 + tid;
    if (i < e) {
      s[j] = src[i];
      d[j] = dst[i];
      rk[j] = atomicAdd(&h[d[j] >> BKT_SHIFT], 1);
    }
  }
  __syncthreads();
  if (tid < nb && h[tid]) base[tid] = atomicAdd(&bcur[tid], h[tid]);
  if (tid + 256 < nb && h[tid + 256]) base[tid + 256] = atomicAdd(&bcur[tid + 256], h[tid + 256]);
  __syncthreads();
#pragma unroll
  for (int j = 0; j < EPB / 256; ++j) {
    int i = b0 + j * 256 + tid;
    if (i < e) {
      int bk = d[j] >> BKT_SHIFT;
      unsigned int dl = (unsigned int)(d[j] & (BKT_NODES - 1));
      part[base[bk] + rk[j]] = (dl << 24) | (unsigned int)s[j];
    }
  }
}

// P2: per-bucket CSR finalize. One block per bucket.
__global__ __launch_bounds__(256) void k_bucket_csr(
    const unsigned int* __restrict__ part, const int* __restrict__ bbase,
    const int* __restrict__ bcnt, int* __restrict__ off, int* __restrict__ end,
    float* __restrict__ dis, int* __restrict__ csr, int n) {
  __shared__ int cnt[256];
  __shared__ int sc[256];
  __shared__ int cur[256];
  int b = blockIdx.x, tid = threadIdx.x;
  int node0 = b << BKT_SHIFT;
  int eb0 = bbase[b];
  int ebn = bcnt[b];
  cnt[tid] = 0;
  __syncthreads();
  for (int i = tid; i < ebn; i += 256) atomicAdd(&cnt[part[eb0 + i] >> 24], 1);
  __syncthreads();
  int v = cnt[tid];
  sc[tid] = v;
  __syncthreads();
  for (int dd = 1; dd < 256; dd <<= 1) {
    int x = (tid >= dd) ? sc[tid - dd] : 0;
    __syncthreads();
    sc[tid] += x;
    __syncthreads();
  }
  int lo = sc[tid] - v;  // exclusive
  cur[tid] = lo;
  int node = node0 + tid;
  if (node < n) {
    off[node] = eb0 + lo;
    end[node] = eb0 + lo + v;
    dis[node] = rsqrtf((float)v + 1.0f);
  }
  __syncthreads();
  for (int i = tid; i < ebn; i += 256) {
    unsigned int u = part[eb0 + i];
    int r = atomicAdd(&cur[u >> 24], 1);
    csr[eb0 + r] = (int)(u & 0xFFFFFFu);
  }
}

// Pre-split W1 and W2 (f32) into k-step-blocked bf16 hi/lo, one launch.
//   Wsp[ks][hl][g][n][8] ; k = ks*32 + g*8 + j
template<int K, int NOUT>
__device__ __forceinline__ void split_w_one(const float* __restrict__ W,
                                            __bf16* __restrict__ Wsp, int idx) {
  int n = idx % NOUT;
  int g = (idx / NOUT) & 3;
  int ks = idx / (4 * NOUT);
  __bf16* hi = Wsp + (size_t)ks * (2 * 4 * NOUT * 8) + ((size_t)g * NOUT + n) * 8;
  __bf16* lo = hi + 4 * NOUT * 8;
#pragma unroll
  for (int j = 0; j < 8; ++j) {
    float f = W[(size_t)(ks * 32 + g * 8 + j) * NOUT + n];
    __bf16 h = (__bf16)f;
    hi[j] = h;
    lo[j] = (__bf16)(f - (float)h);
  }
}

__global__ __launch_bounds__(256) void k_split_w_all(
    const float* __restrict__ W1, __bf16* __restrict__ w1sp,
    const float* __restrict__ W2, __bf16* __restrict__ w2sp) {
  constexpr int N1 = (GCN_IN_C / 32) * 4 * GCN_HID;  // 4096
  constexpr int N2 = (GCN_HID / 32) * 4 * GCN_OUT;   // 1024
  int idx = blockIdx.x * 256 + threadIdx.x;
  if (idx < N1) split_w_one<GCN_IN_C, GCN_HID>(W1, w1sp, idx);
  else if (idx < N1 + N2) split_w_one<GCN_HID, GCN_OUT>(W2, w2sp, idx - N1);
}

// Layer-1 GEMM: W-hi in LDS (staged once), W-lo + A reg-prefetched.
// 3-term split bf16, swapped operands. BM=64, 4 waves x 16 rows.
// T[m] = bf16( dis[m] * (X[m] @ W) ).
template<int K, int NOUT>  // 256, 128
__global__ __launch_bounds__(256) void k_gemm_l1(
    const float* __restrict__ X, const __bf16* __restrict__ Wsp,
    const float* __restrict__ dis, __bf16* __restrict__ T, int M) {
  constexpr int KSTEPS = K / 32;          // 8
  constexpr int NF = NOUT / 16;           // 8
  constexpr int TILE = 2 * 4 * NOUT * 8;  // elems per kstep (hi+lo) = 8192
  constexpr int HI = 4 * NOUT * 8;        // hi elems per kstep = 4096
  __shared__ __bf16 lds[KSTEPS * HI];     // 32768 elems = 64 KB

  const int tid = threadIdx.x;
  const int wave = tid >> 6;
  const int lane = tid & 63;
  const int l15 = lane & 15;
  const int lg = lane >> 4;
  const int r0w = blockIdx.x * 64 + wave * 16;

  // ---- prologue: stage hi of all ksteps into LDS (linear, 1024B chunk/wave/iter)
  {
    constexpr int CHUNKS = KSTEPS * HI * 2 / 1024;  // 64
#pragma unroll
    for (int it = 0; it < CHUNKS / 4; ++it) {
      int c = it * 4 + wave;
      int ks = c >> 3;            // 8 chunks per kstep's hi (8KB)
      int ci = c & 7;
      const char* gs = (const char*)(Wsp + (size_t)ks * TILE) + ci * 1024 + lane * 16;
      char* ls = (char*)lds + (size_t)ks * HI * 2 + ci * 1024;  // wave-uniform base
      __builtin_amdgcn_global_load_lds(
          (const __attribute__((address_space(1))) void*)gs,
          (__attribute__((address_space(3))) void*)ls, 16, 0, 0);
    }
  }

  f32x4 acc[NF];
#pragma unroll
  for (int nf = 0; nf < NF; ++nf) acc[nf] = (f32x4){0.f, 0.f, 0.f, 0.f};

  int row = r0w + l15;
  int rowA = (row < M) ? row : (M - 1);

  const int boff = lg * NOUT * 8 + l15 * 8;  // elem offset within a hi/lo block

  auto loadA = [&](int ks, float4* v0, float4* v1) {
    const float* ap = X + (size_t)rowA * K + ks * 32 + lg * 8;
    *v0 = *(const float4*)ap;
    *v1 = *(const float4*)(ap + 4);
  };
  auto loadBL = [&](int ks, bf16x8* bl) {
    const __bf16* wl = Wsp + (size_t)ks * TILE + HI + boff;
#pragma unroll
    for (int nf = 0; nf < NF; ++nf) bl[nf] = *(const bf16x8*)(wl + nf * 128);
  };

  float4 ca0, ca1, na0, na1;
  bf16x8 blc[NF], bln[NF];
  loadA(0, &ca0, &ca1);
  loadBL(0, blc);
  __syncthreads();  // drain staging; LDS hi ready

#pragma unroll 1
  for (int ks = 0; ks < KSTEPS; ++ks) {
    if (ks + 1 < KSTEPS) {
      loadA(ks + 1, &na0, &na1);
      loadBL(ks + 1, bln);
    }
    // split current A (f32 -> bf16 hi/lo)
    bf16x8 ah, al;
    {
      float va[8] = {ca0.x, ca0.y, ca0.z, ca0.w, ca1.x, ca1.y, ca1.z, ca1.w};
#pragma unroll
      for (int j = 0; j < 8; ++j) {
        __bf16 h = (__bf16)va[j];
        ah[j] = h;
        al[j] = (__bf16)(va[j] - (float)h);
      }
    }
    const __bf16* lh = lds + (size_t)ks * HI + boff;
#pragma unroll
    for (int nf = 0; nf < NF; ++nf) {
      bf16x8 bh = *(const bf16x8*)(lh + nf * 128);
      acc[nf] = __builtin_amdgcn_mfma_f32_16x16x32_bf16(bh, ah, acc[nf], 0, 0, 0);
      acc[nf] = __builtin_amdgcn_mfma_f32_16x16x32_bf16(blc[nf], ah, acc[nf], 0, 0, 0);
      acc[nf] = __builtin_amdgcn_mfma_f32_16x16x32_bf16(bh, al, acc[nf], 0, 0, 0);
    }
    ca0 = na0; ca1 = na1;
#pragma unroll
    for (int nf = 0; nf < NF; ++nf) blc[nf] = bln[nf];
  }

  // epilogue: lane holds T[row][nf*16 + lg*4 + r] -> packed 8B stores
  if (row < M) {
    float dv = dis[row];
#pragma unroll
    for (int nf = 0; nf < NF; ++nf) {
      bf16x4 pk;
#pragma unroll
      for (int r = 0; r < 4; ++r) pk[r] = (__bf16)(dv * acc[nf][r]);
      *(bf16x4*)(T + (size_t)row * NOUT + nf * 16 + lg * 4) = pk;
    }
  }
}

// Layer-2 GEMM: whole Wsp (hi+lo, 32KB) in LDS; A exact bf16 prefetched.
// 2-term, swapped operands. BM=64, 4 waves x 16 rows.
template<int K, int NOUT>  // 128, 64
__global__ __launch_bounds__(256) void k_gemm_l2(
    const __bf16* __restrict__ A, const __bf16* __restrict__ Wsp,
    const float* __restrict__ dis, __bf16* __restrict__ T, int M) {
  constexpr int KSTEPS = K / 32;          // 4
  constexpr int NF = NOUT / 16;           // 4
  constexpr int TILE = 2 * 4 * NOUT * 8;  // 4096 elems per kstep
  constexpr int HL = 4 * NOUT * 8;        // 2048 elems per hi/lo block
  __shared__ __bf16 lds[KSTEPS * TILE];   // 16384 elems = 32 KB

  const int tid = threadIdx.x;
  const int wave = tid >> 6;
  const int lane = tid & 63;
  const int l15 = lane & 15;
  const int lg = lane >> 4;
  const int r0w = blockIdx.x * 64 + wave * 16;

  // ---- prologue: stage whole Wsp (32KB linear)
  {
    constexpr int CHUNKS = KSTEPS * TILE * 2 / 1024;  // 32
#pragma unroll
    for (int it = 0; it < CHUNKS / 4; ++it) {
      int c = it * 4 + wave;
      const char* gs = (const char*)Wsp + c * 1024 + lane * 16;
      char* ls = (char*)lds + c * 1024;
      __builtin_amdgcn_global_load_lds(
          (const __attribute__((address_space(1))) void*)gs,
          (__attribute__((address_space(3))) void*)ls, 16, 0, 0);
    }
  }

  f32x4 acc[NF];
#pragma unroll
  for (int nf = 0; nf < NF; ++nf) acc[nf] = (f32x4){0.f, 0.f, 0.f, 0.f};

  int row = r0w + l15;
  int rowA = (row < M) ? row : (M - 1);
  const int boff = lg * NOUT * 8 + l15 * 8;

  bf16x8 ca, na;
  ca = *(const bf16x8*)(A + (size_t)rowA * K + lg * 8);
  __syncthreads();  // drain staging

#pragma unroll 1
  for (int ks = 0; ks < KSTEPS; ++ks) {
    if (ks + 1 < KSTEPS)
      na = *(const bf16x8*)(A + (size_t)rowA * K + (ks + 1) * 32 + lg * 8);
    const __bf16* lh = lds + (size_t)ks * TILE + boff;
    const __bf16* ll = lh + HL;
#pragma unroll
    for (int nf = 0; nf < NF; ++nf) {
      bf16x8 bh = *(const bf16x8*)(lh + nf * 128);
      bf16x8 bl = *(const bf16x8*)(ll + nf * 128);
      acc[nf] = __builtin_amdgcn_mfma_f32_16x16x32_bf16(bh, ca, acc[nf], 0, 0, 0);
      acc[nf] = __builtin_amdgcn_mfma_f32_16x16x32_bf16(bl, ca, acc[nf], 0, 0, 0);
    }
    ca = na;
  }

  if (row < M) {
    float dv = dis[row];
#pragma unroll
    for (int nf = 0; nf < NF; ++nf) {
      bf16x4 pk;
#pragma unroll
      for (int r = 0; r < 4; ++r) pk[r] = (__bf16)(dv * acc[nf][r]);
      *(bf16x4*)(T + (size_t)row * NOUT + nf * 16 + lg * 4) = pk;
    }
  }
}

// CSR gather aggregation: one LPG-lane group per node (full row per group).
// Contiguous csr per group; 4-deep unroll.
template<int C, bool RELU, typename OutT>
__global__ __launch_bounds__(256) void k_agg_csr(
    const int* __restrict__ csr, const int* __restrict__ off,
    const int* __restrict__ end, const __bf16* __restrict__ ts,
    const float* __restrict__ dis, const float* __restrict__ bias,
    OutT* __restrict__ out, int n) {
  constexpr int LPG = C / 8;   // lanes per group: 16 (C=128), 8 (C=64)
  int gtid = blockIdx.x * 256 + threadIdx.x;
  int node = gtid / LPG;
  int gl = gtid % LPG;
  if (node >= n) return;

  float acc[8];
  {  // self term
    bf16x8 v = *(const bf16x8*)(ts + (size_t)node * C + gl * 8);
#pragma unroll
    for (int j = 0; j < 8; ++j) acc[j] = (float)v[j];
  }

  int e = off[node];
  int e1 = end[node];
  for (; e + 4 <= e1; e += 4) {
    int s0 = csr[e];
    int s1 = csr[e + 1];
    int s2 = csr[e + 2];
    int s3 = csr[e + 3];
    bf16x8 v0 = *(const bf16x8*)(ts + (size_t)s0 * C + gl * 8);
    bf16x8 v1 = *(const bf16x8*)(ts + (size_t)s1 * C + gl * 8);
    bf16x8 v2 = *(const bf16x8*)(ts + (size_t)s2 * C + gl * 8);
    bf16x8 v3 = *(const bf16x8*)(ts + (size_t)s3 * C + gl * 8);
#pragma unroll
    for (int j = 0; j < 8; ++j)
      acc[j] += ((float)v0[j] + (float)v1[j]) + ((float)v2[j] + (float)v3[j]);
  }
  for (; e < e1; ++e) {
    int s0 = csr[e];
    bf16x8 v0 = *(const bf16x8*)(ts + (size_t)s0 * C + gl * 8);
#pragma unroll
    for (int j = 0; j < 8; ++j) acc[j] += (float)v0[j];
  }

  float di = dis[node];
  float o[8];
#pragma unroll
  for (int j = 0; j < 8; ++j) {
    o[j] = di * acc[j] + bias[gl * 8 + j];
    if (RELU) o[j] = fmaxf(o[j], 0.f);
  }
  if constexpr (sizeof(OutT) == 2) {
    bf16x8 pv;
#pragma unroll
    for (int j = 0; j < 8; ++j) pv[j] = (__bf16)o[j];
    *(bf16x8*)((__bf16*)out + (size_t)node * C + gl * 8) = pv;
  } else {
    float4* op = (float4*)((float*)out + (size_t)node * C + gl * 8);
    op[0] = make_float4(o[0], o[1], o[2], o[3]);
    op[1] = make_float4(o[4], o[5], o[6], o[7]);
  }
}

extern "C" void kernel_launch(void* const* d_in, const int* in_sizes, int n_in,
                              void* d_out, int out_size, void* d_ws, size_t ws_size,
                              hipStream_t stream) {
  const float* x  = (const float*)d_in[0];
  const int*   ei = (const int*)d_in[1];
  const float* W1 = (const float*)d_in[2];
  const float* b1 = (const float*)d_in[3];
  const float* W2 = (const float*)d_in[4];
  const float* b2 = (const float*)d_in[5];
  float* out = (float*)d_out;

  const int N = in_sizes[0] / GCN_IN_C;  // 100000
  const int E = in_sizes[1] / 2;         // 1600000
  const int* src = ei;
  const int* dst = ei + E;
  const int NB = (N + BKT_NODES - 1) >> BKT_SHIFT;  // 391 buckets
  const int EB = (E + EPB - 1) / EPB;               // partition blocks

  // ws layout:
  //   dis[N] | t1s(bf16)[N*128] | a1(bf16)[N*128] | off[N] | end[N] | csr[E]
  //   | bcnt|bbase|bcur [512 each] | w1sp | w2sp
  //   part[E] aliases a1 (dead before agg1 writes a1)
  char* p = (char*)d_ws;
  float* dis = (float*)p;             p += (size_t)N * 4;
  __bf16* t1s = (__bf16*)p;           p += (size_t)N * GCN_HID * 2;
  __bf16* a1  = (__bf16*)p;           p += (size_t)N * GCN_HID * 2;
  int* off   = (int*)p;               p += (size_t)N * 4;
  int* end   = (int*)p;               p += (size_t)N * 4;
  int* csr   = (int*)p;               p += (size_t)E * 4;
  int* bcnt  = (int*)p;               p += 512 * 4;
  int* bbase = (int*)p;               p += 512 * 4;
  int* bcur  = (int*)p;               p += 512 * 4;
  __bf16* w1sp = (__bf16*)p;          p += (size_t)(GCN_IN_C / 32) * 2 * 4 * GCN_HID * 8 * 2;
  __bf16* w2sp = (__bf16*)p;
  unsigned int* part = (unsigned int*)a1;  // alias (6.4MB <= 25.6MB, dead before agg1)
  __bf16* t2s = t1s;  // layer-2 table reuses layer-1 table (row stride 64)

  // ---- weight pre-split (one launch) + zero via memset
  k_split_w_all<<<(4096 + 1024 + 255) / 256, 256, 0, stream>>>(W1, w1sp, W2, w2sp);
  hipMemsetAsync(bcnt, 0, 512 * sizeof(int), stream);

  // ---- CSR build (bucketed counting sort)
  k_bucket_hist<<<EB, 256, 0, stream>>>(dst, bcnt, E, NB);
  k_scan_buckets<<<1, 512, 0, stream>>>(bcnt, bbase, bcur, NB);
  k_partition<<<EB, 256, 0, stream>>>(src, dst, bcur, part, E, NB);
  k_bucket_csr<<<NB, 256, 0, stream>>>(part, bbase, bcnt, off, end, dis, csr, N);

  // ---- layer 1: t1s = bf16(dis * x@W1); a1 = bf16(relu(dis*sum + b1))
  k_gemm_l1<GCN_IN_C, GCN_HID>
      <<<(N + 63) / 64, 256, 0, stream>>>(x, w1sp, dis, t1s, N);
  k_agg_csr<GCN_HID, true, __bf16>
      <<<((size_t)N * (GCN_HID / 8) + 255) / 256, 256, 0, stream>>>(csr, off, end, t1s, dis, b1, a1, N);

  // ---- layer 2: t2s = bf16(dis * a1@W2); out = dis*sum + b2
  k_gemm_l2<GCN_HID, GCN_OUT>
      <<<(N + 63) / 64, 256, 0, stream>>>(a1, w2sp, dis, t2s, N);
  k_agg_csr<GCN_OUT, false, float>
      <<<((size_t)N * (GCN_OUT / 8) + 255) / 256, 256, 0, stream>>>(csr, off, end, t2s, dis, b2, out, N);
}